// Round 14
// baseline (505.412 us; speedup 1.0000x reference)
//
#include <hip/hip_runtime.h>

// ---------------------------------------------------------------------------
// Estor: span transformer block on MI355X (gfx950)
// B=8 S=2048 H=768 NH=12 DH=64 SPAN=64 NSP=32 -> 256 spans, 16384 span rows
// tag stage: 65 tokens/span -> 16640 rows
// Workspace: 171,442,176 B base; +25,165,824 B (ff2b) when ws_size allows.
// Round 14: GEMM frozen at R13 (BK=64, 2-slot ring, 1 barrier per 64-K).
//           FFN2 split-K=2 (384 blocks, bf16 partials) summed in LN2,
//           gated on ws_size >= 196,608,000 (fallback: R13 path).
// ---------------------------------------------------------------------------

typedef __attribute__((ext_vector_type(8))) short short8;
typedef __attribute__((ext_vector_type(4))) float f32x4;

typedef const __attribute__((address_space(1))) unsigned int* gas1_t;
typedef __attribute__((address_space(3))) unsigned int* las3_t;

#define DEVI static __device__ __forceinline__

DEVI void gload_lds16(const void* g, void* l){
  // lane i of the wave writes its 16B to (uniform lds base) + i*16
  __builtin_amdgcn_global_load_lds((gas1_t)g, (las3_t)l, 16, 0, 0);
}

template<int N> DEVI void vmcnt_imm(){
  if constexpr (N == 8) asm volatile("s_waitcnt vmcnt(8)" ::: "memory");
  else if constexpr (N == 4) asm volatile("s_waitcnt vmcnt(4)" ::: "memory");
  else asm volatile("s_waitcnt vmcnt(0)" ::: "memory");
}

DEVI unsigned short f2bf(float f){
  union { float f; unsigned u; } v; v.f = f;
  unsigned u = v.u;
  return (unsigned short)((u + 0x7fffu + ((u >> 16) & 1u)) >> 16);
}
DEVI float bf2f(unsigned short h){
  union { unsigned u; float f; } v; v.u = ((unsigned)h) << 16; return v.f;
}

// ---------------- rope table: [2048][384] (cos,sin) ----------------
__global__ void k_ropetab(float2* __restrict__ tab){
  int idx = blockIdx.x * 256 + threadIdx.x;
  if (idx >= 2048 * 384) return;
  int l = idx / 384, i = idx % 384;
  float inv = __expf(-(float)i * (9.210340371976184f / 384.0f)); // 10000^(-i/384)
  float ang = (float)l * inv;
  tab[idx] = make_float2(cosf(ang), sinf(ang));
}

// ---------------- fused f32 -> bf16 convert of all 6 weight tensors ----------------
__global__ void k_f2bf_all(const float* __restrict__ s0, const float* __restrict__ s1,
                           const float* __restrict__ s2, const float* __restrict__ s3,
                           const float* __restrict__ s4, const float* __restrict__ s5,
                           unsigned short* __restrict__ dst){
  int i = blockIdx.x * 256 + threadIdx.x;   // float4 index, total 2359296
  int e = i * 4;
  const float* src; int off;
  if      (e < 1769472){ src = s0; off = e; }
  else if (e < 2359296){ src = s1; off = e - 1769472; }
  else if (e < 4128768){ src = s2; off = e - 2359296; }
  else if (e < 4718592){ src = s3; off = e - 4128768; }
  else if (e < 7077888){ src = s4; off = e - 4718592; }
  else                 { src = s5; off = e - 7077888; }
  float4 v = *(const float4*)(src + off);
  ushort4 o;
  o.x = f2bf(v.x); o.y = f2bf(v.y); o.z = f2bf(v.z); o.w = f2bf(v.w);
  *(ushort4*)(dst + e) = o;
}

// ---------------- gather spans + rope -> bf16 [16384][768] ----------------
__global__ void k_gather_rope(const float* __restrict__ we, const int* __restrict__ starts,
                              const float2* __restrict__ tab, unsigned short* __restrict__ spans){
  int idx = blockIdx.x * 256 + threadIdx.x;       // 16384*192 float4s
  int r  = idx / 192;                              // span-major row
  int c4 = idx % 192;                              // float4 within 768
  int span = r >> 6, s = r & 63;
  int b = span >> 5;
  int l = starts[span] + s;
  float4 x = *(const float4*)(we + ((size_t)b * 2048 + l) * 768 + c4 * 4);
  int i0 = c4 * 2;
  float2 cs0 = tab[l * 384 + i0];
  float2 cs1 = tab[l * 384 + i0 + 1];
  ushort4 o;
  o.x = f2bf(x.x * cs0.x - x.y * cs0.y);
  o.y = f2bf(x.x * cs0.y + x.y * cs0.x);
  o.z = f2bf(x.z * cs1.x - x.w * cs1.y);
  o.w = f2bf(x.z * cs1.y + x.w * cs1.x);
  *(ushort4*)(spans + (size_t)r * 768 + c4 * 4) = o;
}

// ---------------- fill tag rows of at_in [256][65][768] ----------------
__global__ void k_fill_tag(const float* __restrict__ tag_emb, const int* __restrict__ tags,
                           unsigned short* __restrict__ at_in){
  int span = blockIdx.x;
  int tag = tags[span];
  const float* src = tag_emb + (size_t)tag * 768;
  unsigned short* dst = at_in + (size_t)span * 65 * 768;
  for (int j = threadIdx.x; j < 768; j += 256) dst[j] = f2bf(src[j]);
}

// ---------------- GEMM: out[M,N] = A[M,K](bf16) @ W[N,K]^T(bf16) + bias ----------------
// 256x256 tile, 512 threads (8 waves 2x4, per-wave 128x64), BK=64,
// 2-slot LDS ring (128 KB), distance-1 prefetch, ONE vmcnt(0)+s_barrier per
// K-tile. LDS XOR-swizzle: read chunk (g+(kk>>3))^(li&7); stage source chunk
// (l&7)^(l>>3). Block ordering: m204 XCD chunking over 4m x 3n supers.
// EPI: 0 = bias -> bf16
//      1 = bias + residual(bf16, [M,N]) -> bf16 written at row (r + r/64 + 1)  (at_in remap)
//      2 = bias -> f32
//      3 = bias + relu -> bf16
// SPLIT: 1 => split-K=2: grid doubled; blocks [half..) compute K-half 1 with
//        zero bias and write to `resid` (reused as second bf16 output).
template<int EPI, int SPLIT>
__global__ __launch_bounds__(512, 2)
void k_gemm256(const unsigned short* __restrict__ A, const unsigned short* __restrict__ Bw,
               const float* __restrict__ bias, void* __restrict__ outp,
               unsigned short* __restrict__ resid, int M, int N, int K, int nbx)
{
  __shared__ unsigned short Asl[2 * 256 * 64];   // 64 KB: 2 slots x [256 rows][64 cols]
  __shared__ unsigned short Bsl[2 * 256 * 64];   // 64 KB
  const int t0 = threadIdx.x;
  const int w = t0 >> 6, lane = t0 & 63;
  const int g = lane >> 4, li = lane & 15;
  const int wm = w >> 2, wn = w & 3;             // 2 x 4 waves, per-wave 128x64 output

  // ---- split-K decode ----
  int nwg = gridDim.x;
  int bid = blockIdx.x;
  int koff = 0, Keff = K;
  bool sl = false;
  if (SPLIT){
    const int halfg = nwg >> 1;
    sl = bid >= halfg;
    if (sl) bid -= halfg;
    nwg = halfg;
    Keff = K >> 1;
    koff = sl ? Keff : 0;
  }

  // ---- bijective XCD chunking (m204) over the super-tiled raster ----
  const int q = nwg >> 3, r8 = nwg & 7;
  const int xcd = bid & 7, off = bid >> 3;
  const int swz = (xcd < r8 ? xcd * (q + 1) : r8 * (q + 1) + (xcd - r8) * q) + off;
  // ---- super-tile decode: supers of 4m x 3n, m-fastest within ----
  int mt, nt;
  const int main_ = nbx << 6;                    // 64 * nbx
  if (swz >= main_){ mt = 64; nt = swz - main_; }
  else {
    const int s = swz / 12, wv = swz % 12;
    const int nsc = nbx / 3;
    mt = (s / nsc) * 4 + (wv & 3);
    nt = (s % nsc) * 3 + (wv >> 2);
  }
  const int m0 = mt * 256, n0 = nt * 256;

  // staging lane geometry: 8 rows/issue, 8 chunks of 16B per 128B row
  const int srow = lane >> 3;                        // 0..7
  const int sgc = (((lane & 7) ^ (lane >> 3)) << 3); // pre-swizzled source chunk (shorts)
  // fragment-read swizzled chunk offsets (shorts), constant per lane
  const int cs0 = ((g       ^ (li & 7)) << 3);       // kk = 0
  const int cs1 = (((g + 4) ^ (li & 7)) << 3);       // kk = 32

  f32x4 acc[8][4];
  #pragma unroll
  for (int i = 0; i < 8; i++)
    #pragma unroll
    for (int j = 0; j < 4; j++) acc[i][j] = f32x4{0.f, 0.f, 0.f, 0.f};

  const int KT = Keff >> 6;   // K-tiles of 64

  #define STAGE_A64(t_, s_) do { \
    _Pragma("unroll") \
    for (int j = 0; j < 4; j++){ \
      const unsigned short* ga = A + (size_t)(m0 + w*32 + j*8 + srow) * K + koff + (t_)*64 + sgc; \
      gload_lds16(ga, Asl + (s_)*16384 + (w*32 + j*8)*64); \
    } \
  } while(0)
  #define STAGE_B64(t_, s_) do { \
    _Pragma("unroll") \
    for (int j = 0; j < 4; j++){ \
      const unsigned short* gb = Bw + (size_t)(n0 + w*32 + j*8 + srow) * K + koff + (t_)*64 + sgc; \
      gload_lds16(gb, Bsl + (s_)*16384 + (w*32 + j*8)*64); \
    } \
  } while(0)

  // prologue: stage K-tile 0, publish
  STAGE_A64(0, 0);
  STAGE_B64(0, 0);
  vmcnt_imm<0>();
  __builtin_amdgcn_s_barrier();

  for (int t = 0; t < KT; ++t){
    const int slot = t & 1;
    const unsigned short* As = Asl + slot * 16384;
    const unsigned short* Bs = Bsl + slot * 16384;

    // ---- round 0: kk = 0 ----
    short8 af[8], bfr[4];
    #pragma unroll
    for (int m = 0; m < 8; m++)
      af[m] = *(const short8*)(As + (wm * 128 + m * 16 + li) * 64 + cs0);
    #pragma unroll
    for (int n = 0; n < 4; n++)
      bfr[n] = *(const short8*)(Bs + (wn * 64 + n * 16 + li) * 64 + cs0);

    if (t + 1 < KT){                    // stage next tile (other slot), full flight
      STAGE_A64(t + 1, slot ^ 1);
      STAGE_B64(t + 1, slot ^ 1);
    }

    __builtin_amdgcn_s_setprio(1);
    #pragma unroll
    for (int m = 0; m < 8; m++)
      #pragma unroll
      for (int n = 0; n < 4; n++)
        acc[m][n] = __builtin_amdgcn_mfma_f32_16x16x32_bf16(af[m], bfr[n], acc[m][n], 0, 0, 0);
    __builtin_amdgcn_s_setprio(0);

    // ---- round 1: kk = 32 ----
    #pragma unroll
    for (int m = 0; m < 8; m++)
      af[m] = *(const short8*)(As + (wm * 128 + m * 16 + li) * 64 + cs1);
    #pragma unroll
    for (int n = 0; n < 4; n++)
      bfr[n] = *(const short8*)(Bs + (wn * 64 + n * 16 + li) * 64 + cs1);

    __builtin_amdgcn_s_setprio(1);
    #pragma unroll
    for (int m = 0; m < 8; m++)
      #pragma unroll
      for (int n = 0; n < 4; n++)
        acc[m][n] = __builtin_amdgcn_mfma_f32_16x16x32_bf16(af[m], bfr[n], acc[m][n], 0, 0, 0);
    __builtin_amdgcn_s_setprio(0);

    if (t + 1 < KT){
      __builtin_amdgcn_sched_barrier(0);
      vmcnt_imm<0>();                   // next tile's 8 loads: issued ~1 iter ago
      __builtin_amdgcn_s_barrier();
    }
  }
  #undef STAGE_A64
  #undef STAGE_B64

  unsigned short* outb = SPLIT ? (sl ? resid : (unsigned short*)outp)
                               : (unsigned short*)outp;
  float* outf = (float*)outp;
  #pragma unroll
  for (int m = 0; m < 8; m++){
    const int row = m0 + wm * 128 + m * 16 + g * 4;
    #pragma unroll
    for (int n = 0; n < 4; n++){
      const int col = n0 + wn * 64 + n * 16 + li;
      const float bv = (SPLIT && sl) ? 0.f : bias[col];
      #pragma unroll
      for (int r = 0; r < 4; r++){
        float v = acc[m][n][r] + bv;
        const int orow = row + r;
        if (EPI == 1) v += bf2f(resid[(size_t)orow * N + col]);
        if (EPI == 3) v = v > 0.f ? v : 0.f;
        if (EPI == 2 && !SPLIT){
          outf[(size_t)orow * N + col] = v;
        } else if (EPI == 1){
          outb[(size_t)(orow + orow / 64 + 1) * N + col] = f2bf(v);
        } else {
          outb[(size_t)orow * N + col] = f2bf(v);
        }
      }
    }
  }
}

// ---------------- attention: one wave per (span, head) ----------------
// AT=0: 64 tokens (sa). AT=1: 65 tokens with tag at token 0, queries=tokens 1..64 (at).
// qkv: [nrows][2304] bf16, Q at 0, K at 768, V at 1536.  out: [span*64+q][768] bf16.
// V staged to LDS via coalesced ushort4 loads; PV frags from LDS; AT=1 token-64
// contribution applied as an exact rank-1 update (P cols 65.. are exactly 0).
template<int AT>
__global__ __launch_bounds__(64)
void k_attn(const unsigned short* __restrict__ qkv, unsigned short* __restrict__ outp)
{
  constexpr int Lkv  = AT ? 65 : 64;
  constexpr int qoff = AT ? 1 : 0;
  constexpr int NKF  = AT ? 5 : 4;
  constexpr int VK   = AT ? 65 : 64;
  const int h = blockIdx.x;
  const int span = blockIdx.y;
  const int base = span * Lkv;
  const int lane = threadIdx.x;
  const int g = lane >> 4, li = lane & 15;

  __shared__ unsigned short P[64 * 104];
  __shared__ unsigned short Vl[65 * 72 + 8];   // V rows (k), stride 72 u16

  // ---- stage V coalesced (issued first; latency hidden under QK^T+softmax) ----
  {
    const int vrow = lane >> 4;          // 0..3
    const int vcol = (lane & 15) * 4;    // 0..60 (u16)
    #pragma unroll
    for (int k0 = 0; k0 < 64; k0 += 4){
      ushort4 v = *(const ushort4*)(qkv + (size_t)(base + k0 + vrow) * 2304 + 1536 + h * 64 + vcol);
      *(ushort4*)(Vl + (k0 + vrow) * 72 + vcol) = v;
    }
    if (AT) Vl[64 * 72 + lane] = qkv[(size_t)(base + 64) * 2304 + 1536 + h * 64 + lane];
  }

  short8 qf[4][2];
  #pragma unroll
  for (int m = 0; m < 4; m++)
    #pragma unroll
    for (int kq = 0; kq < 2; kq++)
      qf[m][kq] = *(const short8*)(qkv + (size_t)(base + qoff + m * 16 + li) * 2304 + h * 64 + kq * 32 + g * 8);

  f32x4 sc[4][NKF];
  #pragma unroll
  for (int m = 0; m < 4; m++)
    #pragma unroll
    for (int n = 0; n < NKF; n++) sc[m][n] = f32x4{0.f, 0.f, 0.f, 0.f};

  #pragma unroll
  for (int kq = 0; kq < 2; kq++){
    #pragma unroll
    for (int n = 0; n < NKF; n++){
      int krow = n * 16 + li; if (krow >= Lkv) krow = Lkv - 1;
      short8 kf = *(const short8*)(qkv + (size_t)(base + krow) * 2304 + 768 + h * 64 + kq * 32 + g * 8);
      #pragma unroll
      for (int m = 0; m < 4; m++)
        sc[m][n] = __builtin_amdgcn_mfma_f32_16x16x32_bf16(qf[m][kq], kf, sc[m][n], 0, 0, 0);
    }
  }

  const float scale = 0.125f;  // 1/sqrt(64)
  #pragma unroll
  for (int m = 0; m < 4; m++){
    #pragma unroll
    for (int r = 0; r < 4; r++){
      float mx = -1e30f;
      #pragma unroll
      for (int n = 0; n < NKF; n++){
        float v = sc[m][n][r] * scale;
        if (n * 16 + li >= VK) v = -1e30f;
        sc[m][n][r] = v;
        mx = fmaxf(mx, v);
      }
      mx = fmaxf(mx, __shfl_xor(mx, 1, 64));
      mx = fmaxf(mx, __shfl_xor(mx, 2, 64));
      mx = fmaxf(mx, __shfl_xor(mx, 4, 64));
      mx = fmaxf(mx, __shfl_xor(mx, 8, 64));
      float sum = 0.f;
      #pragma unroll
      for (int n = 0; n < NKF; n++){
        float p = __expf(sc[m][n][r] - mx);
        sc[m][n][r] = p;
        sum += p;
      }
      sum += __shfl_xor(sum, 1, 64);
      sum += __shfl_xor(sum, 2, 64);
      sum += __shfl_xor(sum, 4, 64);
      sum += __shfl_xor(sum, 8, 64);
      const float inv = 1.f / sum;
      const int prow = m * 16 + g * 4 + r;
      #pragma unroll
      for (int n = 0; n < NKF; n++)
        P[prow * 104 + n * 16 + li] = f2bf(sc[m][n][r] * inv);
    }
  }
  __syncthreads();

  f32x4 oacc[4][4];
  #pragma unroll
  for (int m = 0; m < 4; m++)
    #pragma unroll
    for (int n = 0; n < 4; n++) oacc[m][n] = f32x4{0.f, 0.f, 0.f, 0.f};

  #pragma unroll
  for (int kp = 0; kp < 2; kp++){
    short8 pf[4];
    #pragma unroll
    for (int m = 0; m < 4; m++)
      pf[m] = *(const short8*)(P + (m * 16 + li) * 104 + kp * 32 + g * 8);
    #pragma unroll
    for (int n = 0; n < 4; n++){
      short8 vf;
      #pragma unroll
      for (int i = 0; i < 8; i++)
        vf[i] = (short)Vl[(kp * 32 + g * 8 + i) * 72 + n * 16 + li];
      #pragma unroll
      for (int m = 0; m < 4; m++)
        oacc[m][n] = __builtin_amdgcn_mfma_f32_16x16x32_bf16(pf[m], vf, oacc[m][n], 0, 0, 0);
    }
  }

  if (AT){
    // token-64 rank-1 update: P cols 65..95 are exactly zero
    float v64[4];
    #pragma unroll
    for (int n = 0; n < 4; n++) v64[n] = bf2f(Vl[64 * 72 + n * 16 + li]);
    #pragma unroll
    for (int m = 0; m < 4; m++)
      #pragma unroll
      for (int r = 0; r < 4; r++){
        float p = bf2f(P[(m * 16 + g * 4 + r) * 104 + 64]);
        #pragma unroll
        for (int n = 0; n < 4; n++) oacc[m][n][r] += p * v64[n];
      }
  }

  #pragma unroll
  for (int m = 0; m < 4; m++)
    #pragma unroll
    for (int n = 0; n < 4; n++)
      #pragma unroll
      for (int r = 0; r < 4; r++){
        int q = m * 16 + g * 4 + r;
        outp[(size_t)(span * 64 + q) * 768 + h * 64 + n * 16 + li] = f2bf(oacc[m][n][r]);
      }
}

// ---------------- LN1: out_emb = LN(raw + 2*(resa+resb)) (span-major -> seq-major), bf16 out ----------------
__global__ __launch_bounds__(256)
void k_ln1(const float* __restrict__ raw, const unsigned short* __restrict__ resa,
           const unsigned short* __restrict__ resb,
           const int* __restrict__ starts, const float* __restrict__ gg,
           const float* __restrict__ bb, unsigned short* __restrict__ oe16)
{
  int wave = threadIdx.x >> 6, lane = threadIdx.x & 63;
  int r = blockIdx.x * 4 + wave;          // span-major row
  int span = r >> 6, s = r & 63;
  int b = span >> 5;
  int l = starts[span] + s;
  const float* rp = raw + ((size_t)b * 2048 + l) * 768;
  const unsigned short* qa = resa + (size_t)r * 768;
  const unsigned short* qb = resb + (size_t)r * 768;
  float x[12];
  float sum = 0.f;
  #pragma unroll
  for (int j = 0; j < 12; j++){
    int c = lane + j * 64;
    x[j] = rp[c] + 2.f * (bf2f(qa[c]) + bf2f(qb[c]));
    sum += x[j];
  }
  #pragma unroll
  for (int o = 1; o < 64; o <<= 1) sum += __shfl_xor(sum, o, 64);
  float mean = sum * (1.f / 768.f);
  float vs = 0.f;
  #pragma unroll
  for (int j = 0; j < 12; j++){ float d = x[j] - mean; vs += d * d; }
  #pragma unroll
  for (int o = 1; o < 64; o <<= 1) vs += __shfl_xor(vs, o, 64);
  float rstd = rsqrtf(vs * (1.f / 768.f) + 1e-12f);
  size_t ob = ((size_t)b * 2048 + l) * 768;
  #pragma unroll
  for (int j = 0; j < 12; j++){
    int c = lane + j * 64;
    float y = (x[j] - mean) * rstd * gg[c] + bb[c];
    oe16[ob + c] = f2bf(y);
  }
}

// ---------------- LN2 + final projection: out[t][0..8] (bf16 inputs) ----------------
// SPLIT: ff2 arrives as two bf16 partials (fa + fb) to be summed.
template<int SPLIT>
__global__ __launch_bounds__(256)
void k_ln2_out(const unsigned short* __restrict__ fa, const unsigned short* __restrict__ fb,
               const unsigned short* __restrict__ oe,
               const float* __restrict__ gg, const float* __restrict__ bb,
               const float* __restrict__ Wout, const float* __restrict__ bout,
               float* __restrict__ out)
{
  int wave = threadIdx.x >> 6, lane = threadIdx.x & 63;
  int t = blockIdx.x * 4 + wave;
  const unsigned short* fpa = fa + (size_t)t * 768;
  const unsigned short* fpb = fb + (size_t)t * 768;
  const unsigned short* ep  = oe + (size_t)t * 768;
  float x[12];
  float sum = 0.f;
  #pragma unroll
  for (int j = 0; j < 12; j++){
    int c = lane + j * 64;
    float f = bf2f(fpa[c]);
    if (SPLIT) f += bf2f(fpb[c]);
    x[j] = f + bf2f(ep[c]);
    sum += x[j];
  }
  #pragma unroll
  for (int o = 1; o < 64; o <<= 1) sum += __shfl_xor(sum, o, 64);
  float mean = sum * (1.f / 768.f);
  float vs = 0.f;
  #pragma unroll
  for (int j = 0; j < 12; j++){ float d = x[j] - mean; vs += d * d; }
  #pragma unroll
  for (int o = 1; o < 64; o <<= 1) vs += __shfl_xor(vs, o, 64);
  float rstd = rsqrtf(vs * (1.f / 768.f) + 1e-12f);
  #pragma unroll
  for (int j = 0; j < 12; j++){
    int c = lane + j * 64;
    x[j] = (x[j] - mean) * rstd * gg[c] + bb[c];
  }
  for (int n = 0; n < 9; n++){
    float p = 0.f;
    #pragma unroll
    for (int j = 0; j < 12; j++){
      int c = lane + j * 64;
      p += x[j] * Wout[n * 768 + c];
    }
    #pragma unroll
    for (int o = 1; o < 64; o <<= 1) p += __shfl_xor(p, o, 64);
    if (lane == 0) out[(size_t)t * 9 + n] = p + bout[n];
  }
}

// ---------------------------------------------------------------------------
extern "C" void kernel_launch(void* const* d_in, const int* in_sizes, int n_in,
                              void* d_out, int out_size, void* d_ws, size_t ws_size,
                              hipStream_t stream)
{
  const float* we      = (const float*)d_in[0];
  const int*   starts  = (const int*)d_in[1];
  const int*   tags    = (const int*)d_in[2];
  const float* tag_emb = (const float*)d_in[3];
  const float* sa_Wqkv = (const float*)d_in[4];
  const float* sa_bqkv = (const float*)d_in[5];
  const float* sa_Wo   = (const float*)d_in[6];
  const float* sa_bo   = (const float*)d_in[7];
  const float* at_Wqkv = (const float*)d_in[8];
  const float* at_bqkv = (const float*)d_in[9];
  const float* at_Wo   = (const float*)d_in[10];
  const float* at_bo   = (const float*)d_in[11];
  const float* an_g    = (const float*)d_in[12];
  const float* an_b    = (const float*)d_in[13];
  const float* W1      = (const float*)d_in[14];
  const float* b1      = (const float*)d_in[15];
  const float* W2      = (const float*)d_in[16];
  const float* b2      = (const float*)d_in[17];
  const float* fn_g    = (const float*)d_in[18];
  const float* fn_b    = (const float*)d_in[19];
  const float* Wout    = (const float*)d_in[20];
  const float* bout    = (const float*)d_in[21];
  float* out = (float*)d_out;
  char* ws = (char*)d_ws;

  // ---- workspace layout, 171,442,176 bytes base (lifetime-aliased) ----
  // phase-1 pool [0 .. 152,567,808):
  unsigned short* spans   = (unsigned short*)(ws + 0);            // 25,165,824  [16384][768]
  unsigned short* at_in   = (unsigned short*)(ws + 25165824);     // 25,559,040  [256][65][768]
  unsigned short* attno   = (unsigned short*)(ws + 50724864);     // 25,165,824  [16384][768]
  unsigned short* qkv     = (unsigned short*)(ws + 75890688);     // 76,677,120  [<=16640][2304]
  float2*         ropetab = (float2*)(ws + 75890688);             //  6,291,456  (dead before qkv write)
  // phase-2 overlays of the (then-dead) pool:
  unsigned short* resa    = (unsigned short*)(ws + 75890688);     // 25,165,824  (over dead qkv)
  unsigned short* resb    = (unsigned short*)(ws + 101056512);    // 25,165,824  (over dead qkv)
  unsigned short* oe16    = (unsigned short*)(ws + 0);            // 25,165,824  (over dead spans)
  unsigned short* ff1     = (unsigned short*)(ws + 25165824);     // 100,663,296 (over dead at_in+attno+res*)
  unsigned short* ff2     = (unsigned short*)(ws + 125829120);    // 25,165,824  (over dead qkv tail)
  // persistent:
  unsigned short* wb      = (unsigned short*)(ws + 152567808);    // 18,874,368  bf16 weights
  unsigned short* sa_Wqkv_b = wb;
  unsigned short* sa_Wo_b   = sa_Wqkv_b + 2304 * 768;
  unsigned short* at_Wqkv_b = sa_Wo_b   + 768 * 768;
  unsigned short* at_Wo_b   = at_Wqkv_b + 2304 * 768;
  unsigned short* W1_b      = at_Wo_b   + 768 * 768;
  unsigned short* W2_b      = W1_b      + 3072 * 768;
  // optional extension (FFN2 split-K second partial):
  unsigned short* ff2b    = (unsigned short*)(ws + 171442176);    // 25,165,824 (if ws allows)
  const bool split_ffn2 = ws_size >= (size_t)(171442176 + 25165824);

  k_ropetab<<<3072, 256, 0, stream>>>(ropetab);
  k_f2bf_all<<<9216, 256, 0, stream>>>(sa_Wqkv, sa_Wo, at_Wqkv, at_Wo, W1, W2, wb);
  k_gather_rope<<<12288, 256, 0, stream>>>(we, starts, ropetab, spans);

  // sa QKV:   [16384,768] @ [2304,768]^T -> qkv   (64x9 = 576)
  k_gemm256<0,0><<<576, 512, 0, stream>>>(spans, sa_Wqkv_b, sa_bqkv, qkv, nullptr, 16384, 2304, 768, 9);
  // sa attention
  k_attn<0><<<dim3(12, 256), 64, 0, stream>>>(qkv, attno);
  // tag rows of at_in
  k_fill_tag<<<256, 256, 0, stream>>>(tag_emb, tags, at_in);
  // sa out-proj + residual(spans), remapped into at_in rows 1..64 per span  (64x3 = 192)
  k_gemm256<1,0><<<192, 512, 0, stream>>>(attno, sa_Wo_b, sa_bo, at_in, spans, 16384, 768, 768, 3);
  // at QKV:  [16640,768] @ [2304,768]^T -> qkv   (65x9 = 585)
  k_gemm256<0,0><<<585, 512, 0, stream>>>(at_in, at_Wqkv_b, at_bqkv, qkv, nullptr, 16640, 2304, 768, 9);
  // at attention (queries = tokens 1..64)
  k_attn<1><<<dim3(12, 256), 64, 0, stream>>>(qkv, attno);
  // at out-proj, split-K=2 -> resa + resb (bf16, span-major)  (2 x 192 = 384 blocks)
  k_gemm256<0,1><<<384, 512, 0, stream>>>(attno, at_Wo_b, at_bo, resa, resb, 16384, 768, 768, 3);
  // LN1: out_emb = LN(raw + 2*(resa+resb)) (scatter folded into row mapping) -> bf16
  k_ln1<<<4096, 256, 0, stream>>>(we, resa, resb, starts, an_g, an_b, oe16);
  // FFN1 + relu -> ff1   (64x12 = 768)
  k_gemm256<3,0><<<768, 512, 0, stream>>>(oe16, W1_b, b1, ff1, nullptr, 16384, 3072, 768, 12);
  // FFN2 -> ff2 (bf16); split-K=2 when workspace allows (384 half-K blocks)
  if (split_ffn2){
    k_gemm256<0,1><<<384, 512, 0, stream>>>(ff1, W2_b, b2, ff2, ff2b, 16384, 768, 3072, 3);
    k_ln2_out<1><<<4096, 256, 0, stream>>>(ff2, ff2b, oe16, fn_g, fn_b, Wout, bout, out);
  } else {
    k_gemm256<0,0><<<192, 512, 0, stream>>>(ff1, W2_b, b2, ff2, nullptr, 16384, 768, 3072, 3);
    k_ln2_out<0><<<4096, 256, 0, stream>>>(ff2, ff2, oe16, fn_g, fn_b, Wout, bout, out);
  }
}

// Round 15
// 485.321 us; speedup vs baseline: 1.0414x; 1.0414x over previous
//
#include <hip/hip_runtime.h>

// ---------------------------------------------------------------------------
// Estor: span transformer block on MI355X (gfx950)
// B=8 S=2048 H=768 NH=12 DH=64 SPAN=64 NSP=32 -> 256 spans, 16384 span rows
// tag stage: 65 tokens/span -> 16640 rows
// Workspace footprint: 171,442,176 bytes (lifetime-aliased; see layout below)
// Round 15: consolidation at the R13 optimum (488us). FFN2 split-K reverted
//           (R14 counters: +19MB FETCH, +25MB WRITE -> net loss). ropetab
//           merged into the weight-convert kernel (one fewer launch).
//           GEMM: BK=64, 2-slot ring, 1 barrier per 64-K (proven).
// ---------------------------------------------------------------------------

typedef __attribute__((ext_vector_type(8))) short short8;
typedef __attribute__((ext_vector_type(4))) float f32x4;

typedef const __attribute__((address_space(1))) unsigned int* gas1_t;
typedef __attribute__((address_space(3))) unsigned int* las3_t;

#define DEVI static __device__ __forceinline__

DEVI void gload_lds16(const void* g, void* l){
  // lane i of the wave writes its 16B to (uniform lds base) + i*16
  __builtin_amdgcn_global_load_lds((gas1_t)g, (las3_t)l, 16, 0, 0);
}

template<int N> DEVI void vmcnt_imm(){
  if constexpr (N == 8) asm volatile("s_waitcnt vmcnt(8)" ::: "memory");
  else if constexpr (N == 4) asm volatile("s_waitcnt vmcnt(4)" ::: "memory");
  else asm volatile("s_waitcnt vmcnt(0)" ::: "memory");
}

DEVI unsigned short f2bf(float f){
  union { float f; unsigned u; } v; v.f = f;
  unsigned u = v.u;
  return (unsigned short)((u + 0x7fffu + ((u >> 16) & 1u)) >> 16);
}
DEVI float bf2f(unsigned short h){
  union { unsigned u; float f; } v; v.u = ((unsigned)h) << 16; return v.f;
}

// ---------------- fused: rope table + f32->bf16 convert of all 6 weights ----------------
// blocks [0,3072): rope table [2048][384] (cos,sin) -> tab
// blocks [3072,12288): weight convert (float4 granularity) -> dst
__global__ void k_prep(float2* __restrict__ tab,
                       const float* __restrict__ s0, const float* __restrict__ s1,
                       const float* __restrict__ s2, const float* __restrict__ s3,
                       const float* __restrict__ s4, const float* __restrict__ s5,
                       unsigned short* __restrict__ dst){
  const int bid = blockIdx.x;
  if (bid < 3072){
    int idx = bid * 256 + threadIdx.x;
    if (idx >= 2048 * 384) return;
    int l = idx / 384, i = idx % 384;
    float inv = __expf(-(float)i * (9.210340371976184f / 384.0f)); // 10000^(-i/384)
    float ang = (float)l * inv;
    tab[idx] = make_float2(cosf(ang), sinf(ang));
    return;
  }
  int i = (bid - 3072) * 256 + threadIdx.x;   // float4 index, total 2359296
  int e = i * 4;
  const float* src; int off;
  if      (e < 1769472){ src = s0; off = e; }
  else if (e < 2359296){ src = s1; off = e - 1769472; }
  else if (e < 4128768){ src = s2; off = e - 2359296; }
  else if (e < 4718592){ src = s3; off = e - 4128768; }
  else if (e < 7077888){ src = s4; off = e - 4718592; }
  else                 { src = s5; off = e - 7077888; }
  float4 v = *(const float4*)(src + off);
  ushort4 o;
  o.x = f2bf(v.x); o.y = f2bf(v.y); o.z = f2bf(v.z); o.w = f2bf(v.w);
  *(ushort4*)(dst + e) = o;
}

// ---------------- gather spans + rope -> bf16 [16384][768] ----------------
__global__ void k_gather_rope(const float* __restrict__ we, const int* __restrict__ starts,
                              const float2* __restrict__ tab, unsigned short* __restrict__ spans){
  int idx = blockIdx.x * 256 + threadIdx.x;       // 16384*192 float4s
  int r  = idx / 192;                              // span-major row
  int c4 = idx % 192;                              // float4 within 768
  int span = r >> 6, s = r & 63;
  int b = span >> 5;
  int l = starts[span] + s;
  float4 x = *(const float4*)(we + ((size_t)b * 2048 + l) * 768 + c4 * 4);
  int i0 = c4 * 2;
  float2 cs0 = tab[l * 384 + i0];
  float2 cs1 = tab[l * 384 + i0 + 1];
  ushort4 o;
  o.x = f2bf(x.x * cs0.x - x.y * cs0.y);
  o.y = f2bf(x.x * cs0.y + x.y * cs0.x);
  o.z = f2bf(x.z * cs1.x - x.w * cs1.y);
  o.w = f2bf(x.z * cs1.y + x.w * cs1.x);
  *(ushort4*)(spans + (size_t)r * 768 + c4 * 4) = o;
}

// ---------------- fill tag rows of at_in [256][65][768] ----------------
__global__ void k_fill_tag(const float* __restrict__ tag_emb, const int* __restrict__ tags,
                           unsigned short* __restrict__ at_in){
  int span = blockIdx.x;
  int tag = tags[span];
  const float* src = tag_emb + (size_t)tag * 768;
  unsigned short* dst = at_in + (size_t)span * 65 * 768;
  for (int j = threadIdx.x; j < 768; j += 256) dst[j] = f2bf(src[j]);
}

// ---------------- GEMM: out[M,N] = A[M,K](bf16) @ W[N,K]^T(bf16) + bias ----------------
// 256x256 tile, 512 threads (8 waves 2x4, per-wave 128x64), BK=64,
// 2-slot LDS ring (128 KB), distance-1 prefetch, ONE vmcnt(0)+s_barrier per
// K-tile. LDS XOR-swizzle: read chunk (g+(kk>>3))^(li&7); stage source chunk
// (l&7)^(l>>3). Block ordering: m204 XCD chunking over 4m x 3n supers.
// EPI: 0 = bias -> bf16
//      1 = bias + residual(bf16, [M,N]) -> bf16 written at row (r + r/64 + 1)  (at_in remap)
//      2 = bias -> f32
//      3 = bias + relu -> bf16
// SPLIT: 1 => split-K=2: grid doubled; blocks [half..) compute K-half 1 with
//        zero bias and write to `resid` (reused as second bf16 output).
template<int EPI, int SPLIT>
__global__ __launch_bounds__(512, 2)
void k_gemm256(const unsigned short* __restrict__ A, const unsigned short* __restrict__ Bw,
               const float* __restrict__ bias, void* __restrict__ outp,
               unsigned short* __restrict__ resid, int M, int N, int K, int nbx)
{
  __shared__ unsigned short Asl[2 * 256 * 64];   // 64 KB: 2 slots x [256 rows][64 cols]
  __shared__ unsigned short Bsl[2 * 256 * 64];   // 64 KB
  const int t0 = threadIdx.x;
  const int w = t0 >> 6, lane = t0 & 63;
  const int g = lane >> 4, li = lane & 15;
  const int wm = w >> 2, wn = w & 3;             // 2 x 4 waves, per-wave 128x64 output

  // ---- split-K decode ----
  int nwg = gridDim.x;
  int bid = blockIdx.x;
  int koff = 0, Keff = K;
  bool sl = false;
  if (SPLIT){
    const int halfg = nwg >> 1;
    sl = bid >= halfg;
    if (sl) bid -= halfg;
    nwg = halfg;
    Keff = K >> 1;
    koff = sl ? Keff : 0;
  }

  // ---- bijective XCD chunking (m204) over the super-tiled raster ----
  const int q = nwg >> 3, r8 = nwg & 7;
  const int xcd = bid & 7, off = bid >> 3;
  const int swz = (xcd < r8 ? xcd * (q + 1) : r8 * (q + 1) + (xcd - r8) * q) + off;
  // ---- super-tile decode: supers of 4m x 3n, m-fastest within ----
  int mt, nt;
  const int main_ = nbx << 6;                    // 64 * nbx
  if (swz >= main_){ mt = 64; nt = swz - main_; }
  else {
    const int s = swz / 12, wv = swz % 12;
    const int nsc = nbx / 3;
    mt = (s / nsc) * 4 + (wv & 3);
    nt = (s % nsc) * 3 + (wv >> 2);
  }
  const int m0 = mt * 256, n0 = nt * 256;

  // staging lane geometry: 8 rows/issue, 8 chunks of 16B per 128B row
  const int srow = lane >> 3;                        // 0..7
  const int sgc = (((lane & 7) ^ (lane >> 3)) << 3); // pre-swizzled source chunk (shorts)
  // fragment-read swizzled chunk offsets (shorts), constant per lane
  const int cs0 = ((g       ^ (li & 7)) << 3);       // kk = 0
  const int cs1 = (((g + 4) ^ (li & 7)) << 3);       // kk = 32

  f32x4 acc[8][4];
  #pragma unroll
  for (int i = 0; i < 8; i++)
    #pragma unroll
    for (int j = 0; j < 4; j++) acc[i][j] = f32x4{0.f, 0.f, 0.f, 0.f};

  const int KT = Keff >> 6;   // K-tiles of 64

  #define STAGE_A64(t_, s_) do { \
    _Pragma("unroll") \
    for (int j = 0; j < 4; j++){ \
      const unsigned short* ga = A + (size_t)(m0 + w*32 + j*8 + srow) * K + koff + (t_)*64 + sgc; \
      gload_lds16(ga, Asl + (s_)*16384 + (w*32 + j*8)*64); \
    } \
  } while(0)
  #define STAGE_B64(t_, s_) do { \
    _Pragma("unroll") \
    for (int j = 0; j < 4; j++){ \
      const unsigned short* gb = Bw + (size_t)(n0 + w*32 + j*8 + srow) * K + koff + (t_)*64 + sgc; \
      gload_lds16(gb, Bsl + (s_)*16384 + (w*32 + j*8)*64); \
    } \
  } while(0)

  // prologue: stage K-tile 0, publish
  STAGE_A64(0, 0);
  STAGE_B64(0, 0);
  vmcnt_imm<0>();
  __builtin_amdgcn_s_barrier();

  for (int t = 0; t < KT; ++t){
    const int slot = t & 1;
    const unsigned short* As = Asl + slot * 16384;
    const unsigned short* Bs = Bsl + slot * 16384;

    // ---- round 0: kk = 0 ----
    short8 af[8], bfr[4];
    #pragma unroll
    for (int m = 0; m < 8; m++)
      af[m] = *(const short8*)(As + (wm * 128 + m * 16 + li) * 64 + cs0);
    #pragma unroll
    for (int n = 0; n < 4; n++)
      bfr[n] = *(const short8*)(Bs + (wn * 64 + n * 16 + li) * 64 + cs0);

    if (t + 1 < KT){                    // stage next tile (other slot), full flight
      STAGE_A64(t + 1, slot ^ 1);
      STAGE_B64(t + 1, slot ^ 1);
    }

    __builtin_amdgcn_s_setprio(1);
    #pragma unroll
    for (int m = 0; m < 8; m++)
      #pragma unroll
      for (int n = 0; n < 4; n++)
        acc[m][n] = __builtin_amdgcn_mfma_f32_16x16x32_bf16(af[m], bfr[n], acc[m][n], 0, 0, 0);
    __builtin_amdgcn_s_setprio(0);

    // ---- round 1: kk = 32 ----
    #pragma unroll
    for (int m = 0; m < 8; m++)
      af[m] = *(const short8*)(As + (wm * 128 + m * 16 + li) * 64 + cs1);
    #pragma unroll
    for (int n = 0; n < 4; n++)
      bfr[n] = *(const short8*)(Bs + (wn * 64 + n * 16 + li) * 64 + cs1);

    __builtin_amdgcn_s_setprio(1);
    #pragma unroll
    for (int m = 0; m < 8; m++)
      #pragma unroll
      for (int n = 0; n < 4; n++)
        acc[m][n] = __builtin_amdgcn_mfma_f32_16x16x32_bf16(af[m], bfr[n], acc[m][n], 0, 0, 0);
    __builtin_amdgcn_s_setprio(0);

    if (t + 1 < KT){
      __builtin_amdgcn_sched_barrier(0);
      vmcnt_imm<0>();                   // next tile's 8 loads: issued ~1 iter ago
      __builtin_amdgcn_s_barrier();
    }
  }
  #undef STAGE_A64
  #undef STAGE_B64

  unsigned short* outb = SPLIT ? (sl ? resid : (unsigned short*)outp)
                               : (unsigned short*)outp;
  float* outf = (float*)outp;
  #pragma unroll
  for (int m = 0; m < 8; m++){
    const int row = m0 + wm * 128 + m * 16 + g * 4;
    #pragma unroll
    for (int n = 0; n < 4; n++){
      const int col = n0 + wn * 64 + n * 16 + li;
      const float bv = (SPLIT && sl) ? 0.f : bias[col];
      #pragma unroll
      for (int r = 0; r < 4; r++){
        float v = acc[m][n][r] + bv;
        const int orow = row + r;
        if (EPI == 1) v += bf2f(resid[(size_t)orow * N + col]);
        if (EPI == 3) v = v > 0.f ? v : 0.f;
        if (EPI == 2 && !SPLIT){
          outf[(size_t)orow * N + col] = v;
        } else if (EPI == 1){
          outb[(size_t)(orow + orow / 64 + 1) * N + col] = f2bf(v);
        } else {
          outb[(size_t)orow * N + col] = f2bf(v);
        }
      }
    }
  }
}

// ---------------- attention: one wave per (span, head) ----------------
// AT=0: 64 tokens (sa). AT=1: 65 tokens with tag at token 0, queries=tokens 1..64 (at).
// qkv: [nrows][2304] bf16, Q at 0, K at 768, V at 1536.  out: [span*64+q][768] bf16.
// V staged to LDS via coalesced ushort4 loads; PV frags from LDS; AT=1 token-64
// contribution applied as an exact rank-1 update (P cols 65.. are exactly 0).
template<int AT>
__global__ __launch_bounds__(64)
void k_attn(const unsigned short* __restrict__ qkv, unsigned short* __restrict__ outp)
{
  constexpr int Lkv  = AT ? 65 : 64;
  constexpr int qoff = AT ? 1 : 0;
  constexpr int NKF  = AT ? 5 : 4;
  constexpr int VK   = AT ? 65 : 64;
  const int h = blockIdx.x;
  const int span = blockIdx.y;
  const int base = span * Lkv;
  const int lane = threadIdx.x;
  const int g = lane >> 4, li = lane & 15;

  __shared__ unsigned short P[64 * 104];
  __shared__ unsigned short Vl[65 * 72 + 8];   // V rows (k), stride 72 u16

  // ---- stage V coalesced (issued first; latency hidden under QK^T+softmax) ----
  {
    const int vrow = lane >> 4;          // 0..3
    const int vcol = (lane & 15) * 4;    // 0..60 (u16)
    #pragma unroll
    for (int k0 = 0; k0 < 64; k0 += 4){
      ushort4 v = *(const ushort4*)(qkv + (size_t)(base + k0 + vrow) * 2304 + 1536 + h * 64 + vcol);
      *(ushort4*)(Vl + (k0 + vrow) * 72 + vcol) = v;
    }
    if (AT) Vl[64 * 72 + lane] = qkv[(size_t)(base + 64) * 2304 + 1536 + h * 64 + lane];
  }

  short8 qf[4][2];
  #pragma unroll
  for (int m = 0; m < 4; m++)
    #pragma unroll
    for (int kq = 0; kq < 2; kq++)
      qf[m][kq] = *(const short8*)(qkv + (size_t)(base + qoff + m * 16 + li) * 2304 + h * 64 + kq * 32 + g * 8);

  f32x4 sc[4][NKF];
  #pragma unroll
  for (int m = 0; m < 4; m++)
    #pragma unroll
    for (int n = 0; n < NKF; n++) sc[m][n] = f32x4{0.f, 0.f, 0.f, 0.f};

  #pragma unroll
  for (int kq = 0; kq < 2; kq++){
    #pragma unroll
    for (int n = 0; n < NKF; n++){
      int krow = n * 16 + li; if (krow >= Lkv) krow = Lkv - 1;
      short8 kf = *(const short8*)(qkv + (size_t)(base + krow) * 2304 + 768 + h * 64 + kq * 32 + g * 8);
      #pragma unroll
      for (int m = 0; m < 4; m++)
        sc[m][n] = __builtin_amdgcn_mfma_f32_16x16x32_bf16(qf[m][kq], kf, sc[m][n], 0, 0, 0);
    }
  }

  const float scale = 0.125f;  // 1/sqrt(64)
  #pragma unroll
  for (int m = 0; m < 4; m++){
    #pragma unroll
    for (int r = 0; r < 4; r++){
      float mx = -1e30f;
      #pragma unroll
      for (int n = 0; n < NKF; n++){
        float v = sc[m][n][r] * scale;
        if (n * 16 + li >= VK) v = -1e30f;
        sc[m][n][r] = v;
        mx = fmaxf(mx, v);
      }
      mx = fmaxf(mx, __shfl_xor(mx, 1, 64));
      mx = fmaxf(mx, __shfl_xor(mx, 2, 64));
      mx = fmaxf(mx, __shfl_xor(mx, 4, 64));
      mx = fmaxf(mx, __shfl_xor(mx, 8, 64));
      float sum = 0.f;
      #pragma unroll
      for (int n = 0; n < NKF; n++){
        float p = __expf(sc[m][n][r] - mx);
        sc[m][n][r] = p;
        sum += p;
      }
      sum += __shfl_xor(sum, 1, 64);
      sum += __shfl_xor(sum, 2, 64);
      sum += __shfl_xor(sum, 4, 64);
      sum += __shfl_xor(sum, 8, 64);
      const float inv = 1.f / sum;
      const int prow = m * 16 + g * 4 + r;
      #pragma unroll
      for (int n = 0; n < NKF; n++)
        P[prow * 104 + n * 16 + li] = f2bf(sc[m][n][r] * inv);
    }
  }
  __syncthreads();

  f32x4 oacc[4][4];
  #pragma unroll
  for (int m = 0; m < 4; m++)
    #pragma unroll
    for (int n = 0; n < 4; n++) oacc[m][n] = f32x4{0.f, 0.f, 0.f, 0.f};

  #pragma unroll
  for (int kp = 0; kp < 2; kp++){
    short8 pf[4];
    #pragma unroll
    for (int m = 0; m < 4; m++)
      pf[m] = *(const short8*)(P + (m * 16 + li) * 104 + kp * 32 + g * 8);
    #pragma unroll
    for (int n = 0; n < 4; n++){
      short8 vf;
      #pragma unroll
      for (int i = 0; i < 8; i++)
        vf[i] = (short)Vl[(kp * 32 + g * 8 + i) * 72 + n * 16 + li];
      #pragma unroll
      for (int m = 0; m < 4; m++)
        oacc[m][n] = __builtin_amdgcn_mfma_f32_16x16x32_bf16(pf[m], vf, oacc[m][n], 0, 0, 0);
    }
  }

  if (AT){
    // token-64 rank-1 update: P cols 65..95 are exactly zero
    float v64[4];
    #pragma unroll
    for (int n = 0; n < 4; n++) v64[n] = bf2f(Vl[64 * 72 + n * 16 + li]);
    #pragma unroll
    for (int m = 0; m < 4; m++)
      #pragma unroll
      for (int r = 0; r < 4; r++){
        float p = bf2f(P[(m * 16 + g * 4 + r) * 104 + 64]);
        #pragma unroll
        for (int n = 0; n < 4; n++) oacc[m][n][r] += p * v64[n];
      }
  }

  #pragma unroll
  for (int m = 0; m < 4; m++)
    #pragma unroll
    for (int n = 0; n < 4; n++)
      #pragma unroll
      for (int r = 0; r < 4; r++){
        int q = m * 16 + g * 4 + r;
        outp[(size_t)(span * 64 + q) * 768 + h * 64 + n * 16 + li] = f2bf(oacc[m][n][r]);
      }
}

// ---------------- LN1: out_emb = LN(raw + 2*(resa+resb)) (span-major -> seq-major), bf16 out ----------------
__global__ __launch_bounds__(256)
void k_ln1(const float* __restrict__ raw, const unsigned short* __restrict__ resa,
           const unsigned short* __restrict__ resb,
           const int* __restrict__ starts, const float* __restrict__ gg,
           const float* __restrict__ bb, unsigned short* __restrict__ oe16)
{
  int wave = threadIdx.x >> 6, lane = threadIdx.x & 63;
  int r = blockIdx.x * 4 + wave;          // span-major row
  int span = r >> 6, s = r & 63;
  int b = span >> 5;
  int l = starts[span] + s;
  const float* rp = raw + ((size_t)b * 2048 + l) * 768;
  const unsigned short* qa = resa + (size_t)r * 768;
  const unsigned short* qb = resb + (size_t)r * 768;
  float x[12];
  float sum = 0.f;
  #pragma unroll
  for (int j = 0; j < 12; j++){
    int c = lane + j * 64;
    x[j] = rp[c] + 2.f * (bf2f(qa[c]) + bf2f(qb[c]));
    sum += x[j];
  }
  #pragma unroll
  for (int o = 1; o < 64; o <<= 1) sum += __shfl_xor(sum, o, 64);
  float mean = sum * (1.f / 768.f);
  float vs = 0.f;
  #pragma unroll
  for (int j = 0; j < 12; j++){ float d = x[j] - mean; vs += d * d; }
  #pragma unroll
  for (int o = 1; o < 64; o <<= 1) vs += __shfl_xor(vs, o, 64);
  float rstd = rsqrtf(vs * (1.f / 768.f) + 1e-12f);
  size_t ob = ((size_t)b * 2048 + l) * 768;
  #pragma unroll
  for (int j = 0; j < 12; j++){
    int c = lane + j * 64;
    float y = (x[j] - mean) * rstd * gg[c] + bb[c];
    oe16[ob + c] = f2bf(y);
  }
}

// ---------------- LN2 + final projection: out[t][0..8] (bf16 inputs) ----------------
__global__ __launch_bounds__(256)
void k_ln2_out(const unsigned short* __restrict__ ff2, const unsigned short* __restrict__ oe,
               const float* __restrict__ gg, const float* __restrict__ bb,
               const float* __restrict__ Wout, const float* __restrict__ bout,
               float* __restrict__ out)
{
  int wave = threadIdx.x >> 6, lane = threadIdx.x & 63;
  int t = blockIdx.x * 4 + wave;
  const unsigned short* fp = ff2 + (size_t)t * 768;
  const unsigned short* ep = oe  + (size_t)t * 768;
  float x[12];
  float sum = 0.f;
  #pragma unroll
  for (int j = 0; j < 12; j++){
    int c = lane + j * 64;
    x[j] = bf2f(fp[c]) + bf2f(ep[c]);
    sum += x[j];
  }
  #pragma unroll
  for (int o = 1; o < 64; o <<= 1) sum += __shfl_xor(sum, o, 64);
  float mean = sum * (1.f / 768.f);
  float vs = 0.f;
  #pragma unroll
  for (int j = 0; j < 12; j++){ float d = x[j] - mean; vs += d * d; }
  #pragma unroll
  for (int o = 1; o < 64; o <<= 1) vs += __shfl_xor(vs, o, 64);
  float rstd = rsqrtf(vs * (1.f / 768.f) + 1e-12f);
  #pragma unroll
  for (int j = 0; j < 12; j++){
    int c = lane + j * 64;
    x[j] = (x[j] - mean) * rstd * gg[c] + bb[c];
  }
  for (int n = 0; n < 9; n++){
    float p = 0.f;
    #pragma unroll
    for (int j = 0; j < 12; j++){
      int c = lane + j * 64;
      p += x[j] * Wout[n * 768 + c];
    }
    #pragma unroll
    for (int o = 1; o < 64; o <<= 1) p += __shfl_xor(p, o, 64);
    if (lane == 0) out[(size_t)t * 9 + n] = p + bout[n];
  }
}

// ---------------------------------------------------------------------------
extern "C" void kernel_launch(void* const* d_in, const int* in_sizes, int n_in,
                              void* d_out, int out_size, void* d_ws, size_t ws_size,
                              hipStream_t stream)
{
  const float* we      = (const float*)d_in[0];
  const int*   starts  = (const int*)d_in[1];
  const int*   tags    = (const int*)d_in[2];
  const float* tag_emb = (const float*)d_in[3];
  const float* sa_Wqkv = (const float*)d_in[4];
  const float* sa_bqkv = (const float*)d_in[5];
  const float* sa_Wo   = (const float*)d_in[6];
  const float* sa_bo   = (const float*)d_in[7];
  const float* at_Wqkv = (const float*)d_in[8];
  const float* at_bqkv = (const float*)d_in[9];
  const float* at_Wo   = (const float*)d_in[10];
  const float* at_bo   = (const float*)d_in[11];
  const float* an_g    = (const float*)d_in[12];
  const float* an_b    = (const float*)d_in[13];
  const float* W1      = (const float*)d_in[14];
  const float* b1      = (const float*)d_in[15];
  const float* W2      = (const float*)d_in[16];
  const float* b2      = (const float*)d_in[17];
  const float* fn_g    = (const float*)d_in[18];
  const float* fn_b    = (const float*)d_in[19];
  const float* Wout    = (const float*)d_in[20];
  const float* bout    = (const float*)d_in[21];
  float* out = (float*)d_out;
  char* ws = (char*)d_ws;

  // ---- workspace layout, 171,442,176 bytes total (lifetime-aliased) ----
  // phase-1 pool [0 .. 152,567,808):
  unsigned short* spans   = (unsigned short*)(ws + 0);            // 25,165,824  [16384][768]
  unsigned short* at_in   = (unsigned short*)(ws + 25165824);     // 25,559,040  [256][65][768]
  unsigned short* attno   = (unsigned short*)(ws + 50724864);     // 25,165,824  [16384][768]
  unsigned short* qkv     = (unsigned short*)(ws + 75890688);     // 76,677,120  [<=16640][2304]
  float2*         ropetab = (float2*)(ws + 75890688);             //  6,291,456  (dead before qkv write)
  // phase-2 overlays of the (then-dead) pool:
  unsigned short* resa    = (unsigned short*)(ws + 75890688);     // 25,165,824  (over dead qkv)
  unsigned short* resb    = (unsigned short*)(ws + 101056512);    // 25,165,824  (over dead qkv)
  unsigned short* oe16    = (unsigned short*)(ws + 0);            // 25,165,824  (over dead spans)
  unsigned short* ff1     = (unsigned short*)(ws + 25165824);     // 100,663,296 (over dead at_in+attno+res*)
  unsigned short* ff2     = (unsigned short*)(ws + 125829120);    // 25,165,824  (over dead qkv tail)
  // persistent:
  unsigned short* wb      = (unsigned short*)(ws + 152567808);    // 18,874,368  bf16 weights
  unsigned short* sa_Wqkv_b = wb;
  unsigned short* sa_Wo_b   = sa_Wqkv_b + 2304 * 768;
  unsigned short* at_Wqkv_b = sa_Wo_b   + 768 * 768;
  unsigned short* at_Wo_b   = at_Wqkv_b + 2304 * 768;
  unsigned short* W1_b      = at_Wo_b   + 768 * 768;
  unsigned short* W2_b      = W1_b      + 3072 * 768;

  // rope table + all weight converts in one launch
  k_prep<<<12288, 256, 0, stream>>>(ropetab, sa_Wqkv, sa_Wo, at_Wqkv, at_Wo, W1, W2, wb);
  k_gather_rope<<<12288, 256, 0, stream>>>(we, starts, ropetab, spans);

  // sa QKV:   [16384,768] @ [2304,768]^T -> qkv   (64x9 = 576)
  k_gemm256<0,0><<<576, 512, 0, stream>>>(spans, sa_Wqkv_b, sa_bqkv, qkv, nullptr, 16384, 2304, 768, 9);
  // sa attention
  k_attn<0><<<dim3(12, 256), 64, 0, stream>>>(qkv, attno);
  // tag rows of at_in
  k_fill_tag<<<256, 256, 0, stream>>>(tag_emb, tags, at_in);
  // sa out-proj + residual(spans), remapped into at_in rows 1..64 per span  (64x3 = 192)
  k_gemm256<1,0><<<192, 512, 0, stream>>>(attno, sa_Wo_b, sa_bo, at_in, spans, 16384, 768, 768, 3);
  // at QKV:  [16640,768] @ [2304,768]^T -> qkv   (65x9 = 585)
  k_gemm256<0,0><<<585, 512, 0, stream>>>(at_in, at_Wqkv_b, at_bqkv, qkv, nullptr, 16640, 2304, 768, 9);
  // at attention (queries = tokens 1..64)
  k_attn<1><<<dim3(12, 256), 64, 0, stream>>>(qkv, attno);
  // at out-proj, split-K=2 -> resa + resb (bf16, span-major)  (2 x 192 = 384 blocks)
  k_gemm256<0,1><<<384, 512, 0, stream>>>(attno, at_Wo_b, at_bo, resa, resb, 16384, 768, 768, 3);
  // LN1: out_emb = LN(raw + 2*(resa+resb)) (scatter folded into row mapping) -> bf16
  k_ln1<<<4096, 256, 0, stream>>>(we, resa, resb, starts, an_g, an_b, oe16);
  // FFN1 + relu -> ff1   (64x12 = 768)
  k_gemm256<3,0><<<768, 512, 0, stream>>>(oe16, W1_b, b1, ff1, nullptr, 16384, 3072, 768, 12);
  // FFN2 -> ff2 (bf16)   (64x3 = 192)
  k_gemm256<0,0><<<192, 512, 0, stream>>>(ff1, W2_b, b2, ff2, nullptr, 16384, 768, 3072, 3);
  // LN2 + final projection
  k_ln2_out<<<4096, 256, 0, stream>>>(ff2, oe16, fn_g, fn_b, Wout, bout, out);
}

// Round 16
// 482.058 us; speedup vs baseline: 1.0484x; 1.0068x over previous
//
#include <hip/hip_runtime.h>

// ---------------------------------------------------------------------------
// Estor: span transformer block on MI355X (gfx950)
// B=8 S=2048 H=768 NH=12 DH=64 SPAN=64 NSP=32 -> 256 spans, 16384 span rows
// tag stage: 65 tokens/span -> 16640 rows
// Workspace footprint: 171,442,176 bytes (lifetime-aliased; see layout below)
// Round 16: R15 + (a) wave-staggered K-half order in GEMM (odd waves compute
//           kk=32 first; commutative, same slot, race-free) to desync LDS
//           bursts from MFMA bursts; (b) fill_tag folded into gather_rope.
// ---------------------------------------------------------------------------

typedef __attribute__((ext_vector_type(8))) short short8;
typedef __attribute__((ext_vector_type(4))) float f32x4;

typedef const __attribute__((address_space(1))) unsigned int* gas1_t;
typedef __attribute__((address_space(3))) unsigned int* las3_t;

#define DEVI static __device__ __forceinline__

DEVI void gload_lds16(const void* g, void* l){
  // lane i of the wave writes its 16B to (uniform lds base) + i*16
  __builtin_amdgcn_global_load_lds((gas1_t)g, (las3_t)l, 16, 0, 0);
}

template<int N> DEVI void vmcnt_imm(){
  if constexpr (N == 8) asm volatile("s_waitcnt vmcnt(8)" ::: "memory");
  else if constexpr (N == 4) asm volatile("s_waitcnt vmcnt(4)" ::: "memory");
  else asm volatile("s_waitcnt vmcnt(0)" ::: "memory");
}

DEVI unsigned short f2bf(float f){
  union { float f; unsigned u; } v; v.f = f;
  unsigned u = v.u;
  return (unsigned short)((u + 0x7fffu + ((u >> 16) & 1u)) >> 16);
}
DEVI float bf2f(unsigned short h){
  union { unsigned u; float f; } v; v.u = ((unsigned)h) << 16; return v.f;
}

// ---------------- fused: rope table + f32->bf16 convert of all 6 weights ----------------
// blocks [0,3072): rope table [2048][384] (cos,sin) -> tab
// blocks [3072,12288): weight convert (float4 granularity) -> dst
__global__ void k_prep(float2* __restrict__ tab,
                       const float* __restrict__ s0, const float* __restrict__ s1,
                       const float* __restrict__ s2, const float* __restrict__ s3,
                       const float* __restrict__ s4, const float* __restrict__ s5,
                       unsigned short* __restrict__ dst){
  const int bid = blockIdx.x;
  if (bid < 3072){
    int idx = bid * 256 + threadIdx.x;
    if (idx >= 2048 * 384) return;
    int l = idx / 384, i = idx % 384;
    float inv = __expf(-(float)i * (9.210340371976184f / 384.0f)); // 10000^(-i/384)
    float ang = (float)l * inv;
    tab[idx] = make_float2(cosf(ang), sinf(ang));
    return;
  }
  int i = (bid - 3072) * 256 + threadIdx.x;   // float4 index, total 2359296
  int e = i * 4;
  const float* src; int off;
  if      (e < 1769472){ src = s0; off = e; }
  else if (e < 2359296){ src = s1; off = e - 1769472; }
  else if (e < 4128768){ src = s2; off = e - 2359296; }
  else if (e < 4718592){ src = s3; off = e - 4128768; }
  else if (e < 7077888){ src = s4; off = e - 4718592; }
  else                 { src = s5; off = e - 7077888; }
  float4 v = *(const float4*)(src + off);
  ushort4 o;
  o.x = f2bf(v.x); o.y = f2bf(v.y); o.z = f2bf(v.z); o.w = f2bf(v.w);
  *(ushort4*)(dst + e) = o;
}

// ---------------- gather spans + rope -> bf16 [16384][768]; + tag rows ----------------
// blocks [0,12288): gather+rope. blocks [12288,12544): fill tag rows of at_in.
__global__ void k_gather_rope(const float* __restrict__ we, const int* __restrict__ starts,
                              const float2* __restrict__ tab, unsigned short* __restrict__ spans,
                              const float* __restrict__ tag_emb, const int* __restrict__ tags,
                              unsigned short* __restrict__ at_in){
  if (blockIdx.x >= 12288){
    int span = blockIdx.x - 12288;
    int tag = tags[span];
    const float* src = tag_emb + (size_t)tag * 768;
    unsigned short* dst = at_in + (size_t)span * 65 * 768;
    for (int j = threadIdx.x; j < 768; j += 256) dst[j] = f2bf(src[j]);
    return;
  }
  int idx = blockIdx.x * 256 + threadIdx.x;       // 16384*192 float4s
  int r  = idx / 192;                              // span-major row
  int c4 = idx % 192;                              // float4 within 768
  int span = r >> 6, s = r & 63;
  int b = span >> 5;
  int l = starts[span] + s;
  float4 x = *(const float4*)(we + ((size_t)b * 2048 + l) * 768 + c4 * 4);
  int i0 = c4 * 2;
  float2 cs0 = tab[l * 384 + i0];
  float2 cs1 = tab[l * 384 + i0 + 1];
  ushort4 o;
  o.x = f2bf(x.x * cs0.x - x.y * cs0.y);
  o.y = f2bf(x.x * cs0.y + x.y * cs0.x);
  o.z = f2bf(x.z * cs1.x - x.w * cs1.y);
  o.w = f2bf(x.z * cs1.y + x.w * cs1.x);
  *(ushort4*)(spans + (size_t)r * 768 + c4 * 4) = o;
}

// ---------------- GEMM: out[M,N] = A[M,K](bf16) @ W[N,K]^T(bf16) + bias ----------------
// 256x256 tile, 512 threads (8 waves 2x4, per-wave 128x64), BK=64,
// 2-slot LDS ring (128 KB), distance-1 prefetch, ONE vmcnt(0)+s_barrier per
// K-tile. LDS XOR-swizzle: read chunk (g+(kk>>3))^(li&7); stage source chunk
// (l&7)^(l>>3). Wave-staggered K-half order (odd waves kk=32 first).
// Block ordering: m204 XCD chunking over 4m x 3n supers.
// EPI: 0 = bias -> bf16
//      1 = bias + residual(bf16, [M,N]) -> bf16 written at row (r + r/64 + 1)  (at_in remap)
//      2 = bias -> f32
//      3 = bias + relu -> bf16
// SPLIT: 1 => split-K=2: grid doubled; blocks [half..) compute K-half 1 with
//        zero bias and write to `resid` (reused as second bf16 output).
template<int EPI, int SPLIT>
__global__ __launch_bounds__(512, 2)
void k_gemm256(const unsigned short* __restrict__ A, const unsigned short* __restrict__ Bw,
               const float* __restrict__ bias, void* __restrict__ outp,
               unsigned short* __restrict__ resid, int M, int N, int K, int nbx)
{
  __shared__ unsigned short Asl[2 * 256 * 64];   // 64 KB: 2 slots x [256 rows][64 cols]
  __shared__ unsigned short Bsl[2 * 256 * 64];   // 64 KB
  const int t0 = threadIdx.x;
  const int w = t0 >> 6, lane = t0 & 63;
  const int g = lane >> 4, li = lane & 15;
  const int wm = w >> 2, wn = w & 3;             // 2 x 4 waves, per-wave 128x64 output

  // ---- split-K decode ----
  int nwg = gridDim.x;
  int bid = blockIdx.x;
  int koff = 0, Keff = K;
  bool sl = false;
  if (SPLIT){
    const int halfg = nwg >> 1;
    sl = bid >= halfg;
    if (sl) bid -= halfg;
    nwg = halfg;
    Keff = K >> 1;
    koff = sl ? Keff : 0;
  }

  // ---- bijective XCD chunking (m204) over the super-tiled raster ----
  const int q = nwg >> 3, r8 = nwg & 7;
  const int xcd = bid & 7, off = bid >> 3;
  const int swz = (xcd < r8 ? xcd * (q + 1) : r8 * (q + 1) + (xcd - r8) * q) + off;
  // ---- super-tile decode: supers of 4m x 3n, m-fastest within ----
  int mt, nt;
  const int main_ = nbx << 6;                    // 64 * nbx
  if (swz >= main_){ mt = 64; nt = swz - main_; }
  else {
    const int s = swz / 12, wv = swz % 12;
    const int nsc = nbx / 3;
    mt = (s / nsc) * 4 + (wv & 3);
    nt = (s % nsc) * 3 + (wv >> 2);
  }
  const int m0 = mt * 256, n0 = nt * 256;

  // staging lane geometry: 8 rows/issue, 8 chunks of 16B per 128B row
  const int srow = lane >> 3;                        // 0..7
  const int sgc = (((lane & 7) ^ (lane >> 3)) << 3); // pre-swizzled source chunk (shorts)
  // fragment-read swizzled chunk offsets (shorts): per-wave staggered half order
  const int csA = (((w & 1) ? (g + 4) : g) ^ (li & 7)) << 3;   // first half this wave
  const int csB = (((w & 1) ? g : (g + 4)) ^ (li & 7)) << 3;   // second half

  f32x4 acc[8][4];
  #pragma unroll
  for (int i = 0; i < 8; i++)
    #pragma unroll
    for (int j = 0; j < 4; j++) acc[i][j] = f32x4{0.f, 0.f, 0.f, 0.f};

  const int KT = Keff >> 6;   // K-tiles of 64

  #define STAGE_A64(t_, s_) do { \
    _Pragma("unroll") \
    for (int j = 0; j < 4; j++){ \
      const unsigned short* ga = A + (size_t)(m0 + w*32 + j*8 + srow) * K + koff + (t_)*64 + sgc; \
      gload_lds16(ga, Asl + (s_)*16384 + (w*32 + j*8)*64); \
    } \
  } while(0)
  #define STAGE_B64(t_, s_) do { \
    _Pragma("unroll") \
    for (int j = 0; j < 4; j++){ \
      const unsigned short* gb = Bw + (size_t)(n0 + w*32 + j*8 + srow) * K + koff + (t_)*64 + sgc; \
      gload_lds16(gb, Bsl + (s_)*16384 + (w*32 + j*8)*64); \
    } \
  } while(0)

  // prologue: stage K-tile 0, publish
  STAGE_A64(0, 0);
  STAGE_B64(0, 0);
  vmcnt_imm<0>();
  __builtin_amdgcn_s_barrier();

  for (int t = 0; t < KT; ++t){
    const int slot = t & 1;
    const unsigned short* As = Asl + slot * 16384;
    const unsigned short* Bs = Bsl + slot * 16384;

    // ---- round 0: this wave's first K-half ----
    short8 af[8], bfr[4];
    #pragma unroll
    for (int m = 0; m < 8; m++)
      af[m] = *(const short8*)(As + (wm * 128 + m * 16 + li) * 64 + csA);
    #pragma unroll
    for (int n = 0; n < 4; n++)
      bfr[n] = *(const short8*)(Bs + (wn * 64 + n * 16 + li) * 64 + csA);

    if (t + 1 < KT){                    // stage next tile (other slot), full flight
      STAGE_A64(t + 1, slot ^ 1);
      STAGE_B64(t + 1, slot ^ 1);
    }

    __builtin_amdgcn_s_setprio(1);
    #pragma unroll
    for (int m = 0; m < 8; m++)
      #pragma unroll
      for (int n = 0; n < 4; n++)
        acc[m][n] = __builtin_amdgcn_mfma_f32_16x16x32_bf16(af[m], bfr[n], acc[m][n], 0, 0, 0);
    __builtin_amdgcn_s_setprio(0);

    // ---- round 1: this wave's second K-half ----
    #pragma unroll
    for (int m = 0; m < 8; m++)
      af[m] = *(const short8*)(As + (wm * 128 + m * 16 + li) * 64 + csB);
    #pragma unroll
    for (int n = 0; n < 4; n++)
      bfr[n] = *(const short8*)(Bs + (wn * 64 + n * 16 + li) * 64 + csB);

    __builtin_amdgcn_s_setprio(1);
    #pragma unroll
    for (int m = 0; m < 8; m++)
      #pragma unroll
      for (int n = 0; n < 4; n++)
        acc[m][n] = __builtin_amdgcn_mfma_f32_16x16x32_bf16(af[m], bfr[n], acc[m][n], 0, 0, 0);
    __builtin_amdgcn_s_setprio(0);

    if (t + 1 < KT){
      __builtin_amdgcn_sched_barrier(0);
      vmcnt_imm<0>();                   // next tile's 8 loads: issued ~1 iter ago
      __builtin_amdgcn_s_barrier();
    }
  }
  #undef STAGE_A64
  #undef STAGE_B64

  unsigned short* outb = SPLIT ? (sl ? resid : (unsigned short*)outp)
                               : (unsigned short*)outp;
  float* outf = (float*)outp;
  #pragma unroll
  for (int m = 0; m < 8; m++){
    const int row = m0 + wm * 128 + m * 16 + g * 4;
    #pragma unroll
    for (int n = 0; n < 4; n++){
      const int col = n0 + wn * 64 + n * 16 + li;
      const float bv = (SPLIT && sl) ? 0.f : bias[col];
      #pragma unroll
      for (int r = 0; r < 4; r++){
        float v = acc[m][n][r] + bv;
        const int orow = row + r;
        if (EPI == 1) v += bf2f(resid[(size_t)orow * N + col]);
        if (EPI == 3) v = v > 0.f ? v : 0.f;
        if (EPI == 2 && !SPLIT){
          outf[(size_t)orow * N + col] = v;
        } else if (EPI == 1){
          outb[(size_t)(orow + orow / 64 + 1) * N + col] = f2bf(v);
        } else {
          outb[(size_t)orow * N + col] = f2bf(v);
        }
      }
    }
  }
}

// ---------------- attention: one wave per (span, head) ----------------
// AT=0: 64 tokens (sa). AT=1: 65 tokens with tag at token 0, queries=tokens 1..64 (at).
// qkv: [nrows][2304] bf16, Q at 0, K at 768, V at 1536.  out: [span*64+q][768] bf16.
// V staged to LDS via coalesced ushort4 loads; PV frags from LDS; AT=1 token-64
// contribution applied as an exact rank-1 update (P cols 65.. are exactly 0).
template<int AT>
__global__ __launch_bounds__(64)
void k_attn(const unsigned short* __restrict__ qkv, unsigned short* __restrict__ outp)
{
  constexpr int Lkv  = AT ? 65 : 64;
  constexpr int qoff = AT ? 1 : 0;
  constexpr int NKF  = AT ? 5 : 4;
  constexpr int VK   = AT ? 65 : 64;
  const int h = blockIdx.x;
  const int span = blockIdx.y;
  const int base = span * Lkv;
  const int lane = threadIdx.x;
  const int g = lane >> 4, li = lane & 15;

  __shared__ unsigned short P[64 * 104];
  __shared__ unsigned short Vl[65 * 72 + 8];   // V rows (k), stride 72 u16

  // ---- stage V coalesced (issued first; latency hidden under QK^T+softmax) ----
  {
    const int vrow = lane >> 4;          // 0..3
    const int vcol = (lane & 15) * 4;    // 0..60 (u16)
    #pragma unroll
    for (int k0 = 0; k0 < 64; k0 += 4){
      ushort4 v = *(const ushort4*)(qkv + (size_t)(base + k0 + vrow) * 2304 + 1536 + h * 64 + vcol);
      *(ushort4*)(Vl + (k0 + vrow) * 72 + vcol) = v;
    }
    if (AT) Vl[64 * 72 + lane] = qkv[(size_t)(base + 64) * 2304 + 1536 + h * 64 + lane];
  }

  short8 qf[4][2];
  #pragma unroll
  for (int m = 0; m < 4; m++)
    #pragma unroll
    for (int kq = 0; kq < 2; kq++)
      qf[m][kq] = *(const short8*)(qkv + (size_t)(base + qoff + m * 16 + li) * 2304 + h * 64 + kq * 32 + g * 8);

  f32x4 sc[4][NKF];
  #pragma unroll
  for (int m = 0; m < 4; m++)
    #pragma unroll
    for (int n = 0; n < NKF; n++) sc[m][n] = f32x4{0.f, 0.f, 0.f, 0.f};

  #pragma unroll
  for (int kq = 0; kq < 2; kq++){
    #pragma unroll
    for (int n = 0; n < NKF; n++){
      int krow = n * 16 + li; if (krow >= Lkv) krow = Lkv - 1;
      short8 kf = *(const short8*)(qkv + (size_t)(base + krow) * 2304 + 768 + h * 64 + kq * 32 + g * 8);
      #pragma unroll
      for (int m = 0; m < 4; m++)
        sc[m][n] = __builtin_amdgcn_mfma_f32_16x16x32_bf16(qf[m][kq], kf, sc[m][n], 0, 0, 0);
    }
  }

  const float scale = 0.125f;  // 1/sqrt(64)
  #pragma unroll
  for (int m = 0; m < 4; m++){
    #pragma unroll
    for (int r = 0; r < 4; r++){
      float mx = -1e30f;
      #pragma unroll
      for (int n = 0; n < NKF; n++){
        float v = sc[m][n][r] * scale;
        if (n * 16 + li >= VK) v = -1e30f;
        sc[m][n][r] = v;
        mx = fmaxf(mx, v);
      }
      mx = fmaxf(mx, __shfl_xor(mx, 1, 64));
      mx = fmaxf(mx, __shfl_xor(mx, 2, 64));
      mx = fmaxf(mx, __shfl_xor(mx, 4, 64));
      mx = fmaxf(mx, __shfl_xor(mx, 8, 64));
      float sum = 0.f;
      #pragma unroll
      for (int n = 0; n < NKF; n++){
        float p = __expf(sc[m][n][r] - mx);
        sc[m][n][r] = p;
        sum += p;
      }
      sum += __shfl_xor(sum, 1, 64);
      sum += __shfl_xor(sum, 2, 64);
      sum += __shfl_xor(sum, 4, 64);
      sum += __shfl_xor(sum, 8, 64);
      const float inv = 1.f / sum;
      const int prow = m * 16 + g * 4 + r;
      #pragma unroll
      for (int n = 0; n < NKF; n++)
        P[prow * 104 + n * 16 + li] = f2bf(sc[m][n][r] * inv);
    }
  }
  __syncthreads();

  f32x4 oacc[4][4];
  #pragma unroll
  for (int m = 0; m < 4; m++)
    #pragma unroll
    for (int n = 0; n < 4; n++) oacc[m][n] = f32x4{0.f, 0.f, 0.f, 0.f};

  #pragma unroll
  for (int kp = 0; kp < 2; kp++){
    short8 pf[4];
    #pragma unroll
    for (int m = 0; m < 4; m++)
      pf[m] = *(const short8*)(P + (m * 16 + li) * 104 + kp * 32 + g * 8);
    #pragma unroll
    for (int n = 0; n < 4; n++){
      short8 vf;
      #pragma unroll
      for (int i = 0; i < 8; i++)
        vf[i] = (short)Vl[(kp * 32 + g * 8 + i) * 72 + n * 16 + li];
      #pragma unroll
      for (int m = 0; m < 4; m++)
        oacc[m][n] = __builtin_amdgcn_mfma_f32_16x16x32_bf16(pf[m], vf, oacc[m][n], 0, 0, 0);
    }
  }

  if (AT){
    // token-64 rank-1 update: P cols 65..95 are exactly zero
    float v64[4];
    #pragma unroll
    for (int n = 0; n < 4; n++) v64[n] = bf2f(Vl[64 * 72 + n * 16 + li]);
    #pragma unroll
    for (int m = 0; m < 4; m++)
      #pragma unroll
      for (int r = 0; r < 4; r++){
        float p = bf2f(P[(m * 16 + g * 4 + r) * 104 + 64]);
        #pragma unroll
        for (int n = 0; n < 4; n++) oacc[m][n][r] += p * v64[n];
      }
  }

  #pragma unroll
  for (int m = 0; m < 4; m++)
    #pragma unroll
    for (int n = 0; n < 4; n++)
      #pragma unroll
      for (int r = 0; r < 4; r++){
        int q = m * 16 + g * 4 + r;
        outp[(size_t)(span * 64 + q) * 768 + h * 64 + n * 16 + li] = f2bf(oacc[m][n][r]);
      }
}

// ---------------- LN1: out_emb = LN(raw + 2*(resa+resb)) (span-major -> seq-major), bf16 out ----------------
__global__ __launch_bounds__(256)
void k_ln1(const float* __restrict__ raw, const unsigned short* __restrict__ resa,
           const unsigned short* __restrict__ resb,
           const int* __restrict__ starts, const float* __restrict__ gg,
           const float* __restrict__ bb, unsigned short* __restrict__ oe16)
{
  int wave = threadIdx.x >> 6, lane = threadIdx.x & 63;
  int r = blockIdx.x * 4 + wave;          // span-major row
  int span = r >> 6, s = r & 63;
  int b = span >> 5;
  int l = starts[span] + s;
  const float* rp = raw + ((size_t)b * 2048 + l) * 768;
  const unsigned short* qa = resa + (size_t)r * 768;
  const unsigned short* qb = resb + (size_t)r * 768;
  float x[12];
  float sum = 0.f;
  #pragma unroll
  for (int j = 0; j < 12; j++){
    int c = lane + j * 64;
    x[j] = rp[c] + 2.f * (bf2f(qa[c]) + bf2f(qb[c]));
    sum += x[j];
  }
  #pragma unroll
  for (int o = 1; o < 64; o <<= 1) sum += __shfl_xor(sum, o, 64);
  float mean = sum * (1.f / 768.f);
  float vs = 0.f;
  #pragma unroll
  for (int j = 0; j < 12; j++){ float d = x[j] - mean; vs += d * d; }
  #pragma unroll
  for (int o = 1; o < 64; o <<= 1) vs += __shfl_xor(vs, o, 64);
  float rstd = rsqrtf(vs * (1.f / 768.f) + 1e-12f);
  size_t ob = ((size_t)b * 2048 + l) * 768;
  #pragma unroll
  for (int j = 0; j < 12; j++){
    int c = lane + j * 64;
    float y = (x[j] - mean) * rstd * gg[c] + bb[c];
    oe16[ob + c] = f2bf(y);
  }
}

// ---------------- LN2 + final projection: out[t][0..8] (bf16 inputs) ----------------
__global__ __launch_bounds__(256)
void k_ln2_out(const unsigned short* __restrict__ ff2, const unsigned short* __restrict__ oe,
               const float* __restrict__ gg, const float* __restrict__ bb,
               const float* __restrict__ Wout, const float* __restrict__ bout,
               float* __restrict__ out)
{
  int wave = threadIdx.x >> 6, lane = threadIdx.x & 63;
  int t = blockIdx.x * 4 + wave;
  const unsigned short* fp = ff2 + (size_t)t * 768;
  const unsigned short* ep = oe  + (size_t)t * 768;
  float x[12];
  float sum = 0.f;
  #pragma unroll
  for (int j = 0; j < 12; j++){
    int c = lane + j * 64;
    x[j] = bf2f(fp[c]) + bf2f(ep[c]);
    sum += x[j];
  }
  #pragma unroll
  for (int o = 1; o < 64; o <<= 1) sum += __shfl_xor(sum, o, 64);
  float mean = sum * (1.f / 768.f);
  float vs = 0.f;
  #pragma unroll
  for (int j = 0; j < 12; j++){ float d = x[j] - mean; vs += d * d; }
  #pragma unroll
  for (int o = 1; o < 64; o <<= 1) vs += __shfl_xor(vs, o, 64);
  float rstd = rsqrtf(vs * (1.f / 768.f) + 1e-12f);
  #pragma unroll
  for (int j = 0; j < 12; j++){
    int c = lane + j * 64;
    x[j] = (x[j] - mean) * rstd * gg[c] + bb[c];
  }
  for (int n = 0; n < 9; n++){
    float p = 0.f;
    #pragma unroll
    for (int j = 0; j < 12; j++){
      int c = lane + j * 64;
      p += x[j] * Wout[n * 768 + c];
    }
    #pragma unroll
    for (int o = 1; o < 64; o <<= 1) p += __shfl_xor(p, o, 64);
    if (lane == 0) out[(size_t)t * 9 + n] = p + bout[n];
  }
}

// ---------------------------------------------------------------------------
extern "C" void kernel_launch(void* const* d_in, const int* in_sizes, int n_in,
                              void* d_out, int out_size, void* d_ws, size_t ws_size,
                              hipStream_t stream)
{
  const float* we      = (const float*)d_in[0];
  const int*   starts  = (const int*)d_in[1];
  const int*   tags    = (const int*)d_in[2];
  const float* tag_emb = (const float*)d_in[3];
  const float* sa_Wqkv = (const float*)d_in[4];
  const float* sa_bqkv = (const float*)d_in[5];
  const float* sa_Wo   = (const float*)d_in[6];
  const float* sa_bo   = (const float*)d_in[7];
  const float* at_Wqkv = (const float*)d_in[8];
  const float* at_bqkv = (const float*)d_in[9];
  const float* at_Wo   = (const float*)d_in[10];
  const float* at_bo   = (const float*)d_in[11];
  const float* an_g    = (const float*)d_in[12];
  const float* an_b    = (const float*)d_in[13];
  const float* W1      = (const float*)d_in[14];
  const float* b1      = (const float*)d_in[15];
  const float* W2      = (const float*)d_in[16];
  const float* b2      = (const float*)d_in[17];
  const float* fn_g    = (const float*)d_in[18];
  const float* fn_b    = (const float*)d_in[19];
  const float* Wout    = (const float*)d_in[20];
  const float* bout    = (const float*)d_in[21];
  float* out = (float*)d_out;
  char* ws = (char*)d_ws;

  // ---- workspace layout, 171,442,176 bytes total (lifetime-aliased) ----
  // phase-1 pool [0 .. 152,567,808):
  unsigned short* spans   = (unsigned short*)(ws + 0);            // 25,165,824  [16384][768]
  unsigned short* at_in   = (unsigned short*)(ws + 25165824);     // 25,559,040  [256][65][768]
  unsigned short* attno   = (unsigned short*)(ws + 50724864);     // 25,165,824  [16384][768]
  unsigned short* qkv     = (unsigned short*)(ws + 75890688);     // 76,677,120  [<=16640][2304]
  float2*         ropetab = (float2*)(ws + 75890688);             //  6,291,456  (dead before qkv write)
  // phase-2 overlays of the (then-dead) pool:
  unsigned short* resa    = (unsigned short*)(ws + 75890688);     // 25,165,824  (over dead qkv)
  unsigned short* resb    = (unsigned short*)(ws + 101056512);    // 25,165,824  (over dead qkv)
  unsigned short* oe16    = (unsigned short*)(ws + 0);            // 25,165,824  (over dead spans)
  unsigned short* ff1     = (unsigned short*)(ws + 25165824);     // 100,663,296 (over dead at_in+attno+res*)
  unsigned short* ff2     = (unsigned short*)(ws + 125829120);    // 25,165,824  (over dead qkv tail)
  // persistent:
  unsigned short* wb      = (unsigned short*)(ws + 152567808);    // 18,874,368  bf16 weights
  unsigned short* sa_Wqkv_b = wb;
  unsigned short* sa_Wo_b   = sa_Wqkv_b + 2304 * 768;
  unsigned short* at_Wqkv_b = sa_Wo_b   + 768 * 768;
  unsigned short* at_Wo_b   = at_Wqkv_b + 2304 * 768;
  unsigned short* W1_b      = at_Wo_b   + 768 * 768;
  unsigned short* W2_b      = W1_b      + 3072 * 768;

  // rope table + all weight converts in one launch
  k_prep<<<12288, 256, 0, stream>>>(ropetab, sa_Wqkv, sa_Wo, at_Wqkv, at_Wo, W1, W2, wb);
  // gather+rope + tag-row fill in one launch
  k_gather_rope<<<12544, 256, 0, stream>>>(we, starts, ropetab, spans, tag_emb, tags, at_in);

  // sa QKV:   [16384,768] @ [2304,768]^T -> qkv   (64x9 = 576)
  k_gemm256<0,0><<<576, 512, 0, stream>>>(spans, sa_Wqkv_b, sa_bqkv, qkv, nullptr, 16384, 2304, 768, 9);
  // sa attention
  k_attn<0><<<dim3(12, 256), 64, 0, stream>>>(qkv, attno);
  // sa out-proj + residual(spans), remapped into at_in rows 1..64 per span  (64x3 = 192)
  k_gemm256<1,0><<<192, 512, 0, stream>>>(attno, sa_Wo_b, sa_bo, at_in, spans, 16384, 768, 768, 3);
  // at QKV:  [16640,768] @ [2304,768]^T -> qkv   (65x9 = 585)
  k_gemm256<0,0><<<585, 512, 0, stream>>>(at_in, at_Wqkv_b, at_bqkv, qkv, nullptr, 16640, 2304, 768, 9);
  // at attention (queries = tokens 1..64)
  k_attn<1><<<dim3(12, 256), 64, 0, stream>>>(qkv, attno);
  // at out-proj, split-K=2 -> resa + resb (bf16, span-major)  (2 x 192 = 384 blocks)
  k_gemm256<0,1><<<384, 512, 0, stream>>>(attno, at_Wo_b, at_bo, resa, resb, 16384, 768, 768, 3);
  // LN1: out_emb = LN(raw + 2*(resa+resb)) (scatter folded into row mapping) -> bf16
  k_ln1<<<4096, 256, 0, stream>>>(we, resa, resb, starts, an_g, an_b, oe16);
  // FFN1 + relu -> ff1   (64x12 = 768)
  k_gemm256<3,0><<<768, 512, 0, stream>>>(oe16, W1_b, b1, ff1, nullptr, 16384, 3072, 768, 12);
  // FFN2 -> ff2 (bf16)   (64x3 = 192)
  k_gemm256<0,0><<<192, 512, 0, stream>>>(ff1, W2_b, b2, ff2, nullptr, 16384, 768, 3072, 3);
  // LN2 + final projection
  k_ln2_out<<<4096, 256, 0, stream>>>(ff2, oe16, fn_g, fn_b, Wout, bout, out);
}

// Round 17
// 481.318 us; speedup vs baseline: 1.0501x; 1.0015x over previous
//
#include <hip/hip_runtime.h>

// ---------------------------------------------------------------------------
// Estor: span transformer block on MI355X (gfx950)
// B=8 S=2048 H=768 NH=12 DH=64 SPAN=64 NSP=32 -> 256 spans, 16384 span rows
// tag stage: 65 tokens/span -> 16640 rows
// Workspace footprint: 171,442,176 bytes (lifetime-aliased; see layout below)
// Round 17: R16 frozen (GEMM BK=64/2-slot/1-barrier, staggered halves;
//           fused prep + gather). New: LN1/LN2 fully vectorized
//           (float4/ushort4 lane-major loads incl. gains/bias/Wout).
// ---------------------------------------------------------------------------

typedef __attribute__((ext_vector_type(8))) short short8;
typedef __attribute__((ext_vector_type(4))) float f32x4;

typedef const __attribute__((address_space(1))) unsigned int* gas1_t;
typedef __attribute__((address_space(3))) unsigned int* las3_t;

#define DEVI static __device__ __forceinline__

DEVI void gload_lds16(const void* g, void* l){
  // lane i of the wave writes its 16B to (uniform lds base) + i*16
  __builtin_amdgcn_global_load_lds((gas1_t)g, (las3_t)l, 16, 0, 0);
}

template<int N> DEVI void vmcnt_imm(){
  if constexpr (N == 8) asm volatile("s_waitcnt vmcnt(8)" ::: "memory");
  else if constexpr (N == 4) asm volatile("s_waitcnt vmcnt(4)" ::: "memory");
  else asm volatile("s_waitcnt vmcnt(0)" ::: "memory");
}

DEVI unsigned short f2bf(float f){
  union { float f; unsigned u; } v; v.f = f;
  unsigned u = v.u;
  return (unsigned short)((u + 0x7fffu + ((u >> 16) & 1u)) >> 16);
}
DEVI float bf2f(unsigned short h){
  union { unsigned u; float f; } v; v.u = ((unsigned)h) << 16; return v.f;
}

// ---------------- fused: rope table + f32->bf16 convert of all 6 weights ----------------
__global__ void k_prep(float2* __restrict__ tab,
                       const float* __restrict__ s0, const float* __restrict__ s1,
                       const float* __restrict__ s2, const float* __restrict__ s3,
                       const float* __restrict__ s4, const float* __restrict__ s5,
                       unsigned short* __restrict__ dst){
  const int bid = blockIdx.x;
  if (bid < 3072){
    int idx = bid * 256 + threadIdx.x;
    if (idx >= 2048 * 384) return;
    int l = idx / 384, i = idx % 384;
    float inv = __expf(-(float)i * (9.210340371976184f / 384.0f)); // 10000^(-i/384)
    float ang = (float)l * inv;
    tab[idx] = make_float2(cosf(ang), sinf(ang));
    return;
  }
  int i = (bid - 3072) * 256 + threadIdx.x;   // float4 index, total 2359296
  int e = i * 4;
  const float* src; int off;
  if      (e < 1769472){ src = s0; off = e; }
  else if (e < 2359296){ src = s1; off = e - 1769472; }
  else if (e < 4128768){ src = s2; off = e - 2359296; }
  else if (e < 4718592){ src = s3; off = e - 4128768; }
  else if (e < 7077888){ src = s4; off = e - 4718592; }
  else                 { src = s5; off = e - 7077888; }
  float4 v = *(const float4*)(src + off);
  ushort4 o;
  o.x = f2bf(v.x); o.y = f2bf(v.y); o.z = f2bf(v.z); o.w = f2bf(v.w);
  *(ushort4*)(dst + e) = o;
}

// ---------------- gather spans + rope -> bf16 [16384][768]; + tag rows ----------------
__global__ void k_gather_rope(const float* __restrict__ we, const int* __restrict__ starts,
                              const float2* __restrict__ tab, unsigned short* __restrict__ spans,
                              const float* __restrict__ tag_emb, const int* __restrict__ tags,
                              unsigned short* __restrict__ at_in){
  if (blockIdx.x >= 12288){
    int span = blockIdx.x - 12288;
    int tag = tags[span];
    const float* src = tag_emb + (size_t)tag * 768;
    unsigned short* dst = at_in + (size_t)span * 65 * 768;
    for (int j = threadIdx.x; j < 768; j += 256) dst[j] = f2bf(src[j]);
    return;
  }
  int idx = blockIdx.x * 256 + threadIdx.x;       // 16384*192 float4s
  int r  = idx / 192;                              // span-major row
  int c4 = idx % 192;                              // float4 within 768
  int span = r >> 6, s = r & 63;
  int b = span >> 5;
  int l = starts[span] + s;
  float4 x = *(const float4*)(we + ((size_t)b * 2048 + l) * 768 + c4 * 4);
  int i0 = c4 * 2;
  float2 cs0 = tab[l * 384 + i0];
  float2 cs1 = tab[l * 384 + i0 + 1];
  ushort4 o;
  o.x = f2bf(x.x * cs0.x - x.y * cs0.y);
  o.y = f2bf(x.x * cs0.y + x.y * cs0.x);
  o.z = f2bf(x.z * cs1.x - x.w * cs1.y);
  o.w = f2bf(x.z * cs1.y + x.w * cs1.x);
  *(ushort4*)(spans + (size_t)r * 768 + c4 * 4) = o;
}

// ---------------- GEMM: out[M,N] = A[M,K](bf16) @ W[N,K]^T(bf16) + bias ----------------
// 256x256 tile, 512 threads (8 waves 2x4, per-wave 128x64), BK=64,
// 2-slot LDS ring (128 KB), distance-1 prefetch, ONE vmcnt(0)+s_barrier per
// K-tile. LDS XOR-swizzle; wave-staggered K-half order; m204 XCD chunking
// over 4m x 3n supers.
// EPI: 0 bias->bf16 | 1 bias+residual->bf16 remapped | 2 bias->f32 | 3 bias+relu->bf16
// SPLIT: 1 => split-K=2 (second half -> resid buffer, zero bias).
template<int EPI, int SPLIT>
__global__ __launch_bounds__(512, 2)
void k_gemm256(const unsigned short* __restrict__ A, const unsigned short* __restrict__ Bw,
               const float* __restrict__ bias, void* __restrict__ outp,
               unsigned short* __restrict__ resid, int M, int N, int K, int nbx)
{
  __shared__ unsigned short Asl[2 * 256 * 64];   // 64 KB: 2 slots x [256 rows][64 cols]
  __shared__ unsigned short Bsl[2 * 256 * 64];   // 64 KB
  const int t0 = threadIdx.x;
  const int w = t0 >> 6, lane = t0 & 63;
  const int g = lane >> 4, li = lane & 15;
  const int wm = w >> 2, wn = w & 3;             // 2 x 4 waves, per-wave 128x64 output

  // ---- split-K decode ----
  int nwg = gridDim.x;
  int bid = blockIdx.x;
  int koff = 0, Keff = K;
  bool sl = false;
  if (SPLIT){
    const int halfg = nwg >> 1;
    sl = bid >= halfg;
    if (sl) bid -= halfg;
    nwg = halfg;
    Keff = K >> 1;
    koff = sl ? Keff : 0;
  }

  // ---- bijective XCD chunking (m204) over the super-tiled raster ----
  const int q = nwg >> 3, r8 = nwg & 7;
  const int xcd = bid & 7, off = bid >> 3;
  const int swz = (xcd < r8 ? xcd * (q + 1) : r8 * (q + 1) + (xcd - r8) * q) + off;
  // ---- super-tile decode: supers of 4m x 3n, m-fastest within ----
  int mt, nt;
  const int main_ = nbx << 6;                    // 64 * nbx
  if (swz >= main_){ mt = 64; nt = swz - main_; }
  else {
    const int s = swz / 12, wv = swz % 12;
    const int nsc = nbx / 3;
    mt = (s / nsc) * 4 + (wv & 3);
    nt = (s % nsc) * 3 + (wv >> 2);
  }
  const int m0 = mt * 256, n0 = nt * 256;

  // staging lane geometry: 8 rows/issue, 8 chunks of 16B per 128B row
  const int srow = lane >> 3;                        // 0..7
  const int sgc = (((lane & 7) ^ (lane >> 3)) << 3); // pre-swizzled source chunk (shorts)
  // fragment-read swizzled chunk offsets (shorts): per-wave staggered half order
  const int csA = (((w & 1) ? (g + 4) : g) ^ (li & 7)) << 3;   // first half this wave
  const int csB = (((w & 1) ? g : (g + 4)) ^ (li & 7)) << 3;   // second half

  f32x4 acc[8][4];
  #pragma unroll
  for (int i = 0; i < 8; i++)
    #pragma unroll
    for (int j = 0; j < 4; j++) acc[i][j] = f32x4{0.f, 0.f, 0.f, 0.f};

  const int KT = Keff >> 6;   // K-tiles of 64

  #define STAGE_A64(t_, s_) do { \
    _Pragma("unroll") \
    for (int j = 0; j < 4; j++){ \
      const unsigned short* ga = A + (size_t)(m0 + w*32 + j*8 + srow) * K + koff + (t_)*64 + sgc; \
      gload_lds16(ga, Asl + (s_)*16384 + (w*32 + j*8)*64); \
    } \
  } while(0)
  #define STAGE_B64(t_, s_) do { \
    _Pragma("unroll") \
    for (int j = 0; j < 4; j++){ \
      const unsigned short* gb = Bw + (size_t)(n0 + w*32 + j*8 + srow) * K + koff + (t_)*64 + sgc; \
      gload_lds16(gb, Bsl + (s_)*16384 + (w*32 + j*8)*64); \
    } \
  } while(0)

  // prologue: stage K-tile 0, publish
  STAGE_A64(0, 0);
  STAGE_B64(0, 0);
  vmcnt_imm<0>();
  __builtin_amdgcn_s_barrier();

  for (int t = 0; t < KT; ++t){
    const int slot = t & 1;
    const unsigned short* As = Asl + slot * 16384;
    const unsigned short* Bs = Bsl + slot * 16384;

    // ---- round 0: this wave's first K-half ----
    short8 af[8], bfr[4];
    #pragma unroll
    for (int m = 0; m < 8; m++)
      af[m] = *(const short8*)(As + (wm * 128 + m * 16 + li) * 64 + csA);
    #pragma unroll
    for (int n = 0; n < 4; n++)
      bfr[n] = *(const short8*)(Bs + (wn * 64 + n * 16 + li) * 64 + csA);

    if (t + 1 < KT){                    // stage next tile (other slot), full flight
      STAGE_A64(t + 1, slot ^ 1);
      STAGE_B64(t + 1, slot ^ 1);
    }

    __builtin_amdgcn_s_setprio(1);
    #pragma unroll
    for (int m = 0; m < 8; m++)
      #pragma unroll
      for (int n = 0; n < 4; n++)
        acc[m][n] = __builtin_amdgcn_mfma_f32_16x16x32_bf16(af[m], bfr[n], acc[m][n], 0, 0, 0);
    __builtin_amdgcn_s_setprio(0);

    // ---- round 1: this wave's second K-half ----
    #pragma unroll
    for (int m = 0; m < 8; m++)
      af[m] = *(const short8*)(As + (wm * 128 + m * 16 + li) * 64 + csB);
    #pragma unroll
    for (int n = 0; n < 4; n++)
      bfr[n] = *(const short8*)(Bs + (wn * 64 + n * 16 + li) * 64 + csB);

    __builtin_amdgcn_s_setprio(1);
    #pragma unroll
    for (int m = 0; m < 8; m++)
      #pragma unroll
      for (int n = 0; n < 4; n++)
        acc[m][n] = __builtin_amdgcn_mfma_f32_16x16x32_bf16(af[m], bfr[n], acc[m][n], 0, 0, 0);
    __builtin_amdgcn_s_setprio(0);

    if (t + 1 < KT){
      __builtin_amdgcn_sched_barrier(0);
      vmcnt_imm<0>();                   // next tile's 8 loads: issued ~1 iter ago
      __builtin_amdgcn_s_barrier();
    }
  }
  #undef STAGE_A64
  #undef STAGE_B64

  unsigned short* outb = SPLIT ? (sl ? resid : (unsigned short*)outp)
                               : (unsigned short*)outp;
  float* outf = (float*)outp;
  #pragma unroll
  for (int m = 0; m < 8; m++){
    const int row = m0 + wm * 128 + m * 16 + g * 4;
    #pragma unroll
    for (int n = 0; n < 4; n++){
      const int col = n0 + wn * 64 + n * 16 + li;
      const float bv = (SPLIT && sl) ? 0.f : bias[col];
      #pragma unroll
      for (int r = 0; r < 4; r++){
        float v = acc[m][n][r] + bv;
        const int orow = row + r;
        if (EPI == 1) v += bf2f(resid[(size_t)orow * N + col]);
        if (EPI == 3) v = v > 0.f ? v : 0.f;
        if (EPI == 2 && !SPLIT){
          outf[(size_t)orow * N + col] = v;
        } else if (EPI == 1){
          outb[(size_t)(orow + orow / 64 + 1) * N + col] = f2bf(v);
        } else {
          outb[(size_t)orow * N + col] = f2bf(v);
        }
      }
    }
  }
}

// ---------------- attention: one wave per (span, head) ----------------
template<int AT>
__global__ __launch_bounds__(64)
void k_attn(const unsigned short* __restrict__ qkv, unsigned short* __restrict__ outp)
{
  constexpr int Lkv  = AT ? 65 : 64;
  constexpr int qoff = AT ? 1 : 0;
  constexpr int NKF  = AT ? 5 : 4;
  constexpr int VK   = AT ? 65 : 64;
  const int h = blockIdx.x;
  const int span = blockIdx.y;
  const int base = span * Lkv;
  const int lane = threadIdx.x;
  const int g = lane >> 4, li = lane & 15;

  __shared__ unsigned short P[64 * 104];
  __shared__ unsigned short Vl[65 * 72 + 8];   // V rows (k), stride 72 u16

  // ---- stage V coalesced (issued first; latency hidden under QK^T+softmax) ----
  {
    const int vrow = lane >> 4;          // 0..3
    const int vcol = (lane & 15) * 4;    // 0..60 (u16)
    #pragma unroll
    for (int k0 = 0; k0 < 64; k0 += 4){
      ushort4 v = *(const ushort4*)(qkv + (size_t)(base + k0 + vrow) * 2304 + 1536 + h * 64 + vcol);
      *(ushort4*)(Vl + (k0 + vrow) * 72 + vcol) = v;
    }
    if (AT) Vl[64 * 72 + lane] = qkv[(size_t)(base + 64) * 2304 + 1536 + h * 64 + lane];
  }

  short8 qf[4][2];
  #pragma unroll
  for (int m = 0; m < 4; m++)
    #pragma unroll
    for (int kq = 0; kq < 2; kq++)
      qf[m][kq] = *(const short8*)(qkv + (size_t)(base + qoff + m * 16 + li) * 2304 + h * 64 + kq * 32 + g * 8);

  f32x4 sc[4][NKF];
  #pragma unroll
  for (int m = 0; m < 4; m++)
    #pragma unroll
    for (int n = 0; n < NKF; n++) sc[m][n] = f32x4{0.f, 0.f, 0.f, 0.f};

  #pragma unroll
  for (int kq = 0; kq < 2; kq++){
    #pragma unroll
    for (int n = 0; n < NKF; n++){
      int krow = n * 16 + li; if (krow >= Lkv) krow = Lkv - 1;
      short8 kf = *(const short8*)(qkv + (size_t)(base + krow) * 2304 + 768 + h * 64 + kq * 32 + g * 8);
      #pragma unroll
      for (int m = 0; m < 4; m++)
        sc[m][n] = __builtin_amdgcn_mfma_f32_16x16x32_bf16(qf[m][kq], kf, sc[m][n], 0, 0, 0);
    }
  }

  const float scale = 0.125f;  // 1/sqrt(64)
  #pragma unroll
  for (int m = 0; m < 4; m++){
    #pragma unroll
    for (int r = 0; r < 4; r++){
      float mx = -1e30f;
      #pragma unroll
      for (int n = 0; n < NKF; n++){
        float v = sc[m][n][r] * scale;
        if (n * 16 + li >= VK) v = -1e30f;
        sc[m][n][r] = v;
        mx = fmaxf(mx, v);
      }
      mx = fmaxf(mx, __shfl_xor(mx, 1, 64));
      mx = fmaxf(mx, __shfl_xor(mx, 2, 64));
      mx = fmaxf(mx, __shfl_xor(mx, 4, 64));
      mx = fmaxf(mx, __shfl_xor(mx, 8, 64));
      float sum = 0.f;
      #pragma unroll
      for (int n = 0; n < NKF; n++){
        float p = __expf(sc[m][n][r] - mx);
        sc[m][n][r] = p;
        sum += p;
      }
      sum += __shfl_xor(sum, 1, 64);
      sum += __shfl_xor(sum, 2, 64);
      sum += __shfl_xor(sum, 4, 64);
      sum += __shfl_xor(sum, 8, 64);
      const float inv = 1.f / sum;
      const int prow = m * 16 + g * 4 + r;
      #pragma unroll
      for (int n = 0; n < NKF; n++)
        P[prow * 104 + n * 16 + li] = f2bf(sc[m][n][r] * inv);
    }
  }
  __syncthreads();

  f32x4 oacc[4][4];
  #pragma unroll
  for (int m = 0; m < 4; m++)
    #pragma unroll
    for (int n = 0; n < 4; n++) oacc[m][n] = f32x4{0.f, 0.f, 0.f, 0.f};

  #pragma unroll
  for (int kp = 0; kp < 2; kp++){
    short8 pf[4];
    #pragma unroll
    for (int m = 0; m < 4; m++)
      pf[m] = *(const short8*)(P + (m * 16 + li) * 104 + kp * 32 + g * 8);
    #pragma unroll
    for (int n = 0; n < 4; n++){
      short8 vf;
      #pragma unroll
      for (int i = 0; i < 8; i++)
        vf[i] = (short)Vl[(kp * 32 + g * 8 + i) * 72 + n * 16 + li];
      #pragma unroll
      for (int m = 0; m < 4; m++)
        oacc[m][n] = __builtin_amdgcn_mfma_f32_16x16x32_bf16(pf[m], vf, oacc[m][n], 0, 0, 0);
    }
  }

  if (AT){
    // token-64 rank-1 update: P cols 65..95 are exactly zero
    float v64[4];
    #pragma unroll
    for (int n = 0; n < 4; n++) v64[n] = bf2f(Vl[64 * 72 + n * 16 + li]);
    #pragma unroll
    for (int m = 0; m < 4; m++)
      #pragma unroll
      for (int r = 0; r < 4; r++){
        float p = bf2f(P[(m * 16 + g * 4 + r) * 104 + 64]);
        #pragma unroll
        for (int n = 0; n < 4; n++) oacc[m][n][r] += p * v64[n];
      }
  }

  #pragma unroll
  for (int m = 0; m < 4; m++)
    #pragma unroll
    for (int n = 0; n < 4; n++)
      #pragma unroll
      for (int r = 0; r < 4; r++){
        int q = m * 16 + g * 4 + r;
        outp[(size_t)(span * 64 + q) * 768 + h * 64 + n * 16 + li] = f2bf(oacc[m][n][r]);
      }
}

// ---------------- LN1: out_emb = LN(raw + 2*(resa+resb)), vectorized ----------------
__global__ __launch_bounds__(256)
void k_ln1(const float* __restrict__ raw, const unsigned short* __restrict__ resa,
           const unsigned short* __restrict__ resb,
           const int* __restrict__ starts, const float* __restrict__ gg,
           const float* __restrict__ bb, unsigned short* __restrict__ oe16)
{
  int wave = threadIdx.x >> 6, lane = threadIdx.x & 63;
  int r = blockIdx.x * 4 + wave;          // span-major row
  int span = r >> 6, s = r & 63;
  int b = span >> 5;
  int l = starts[span] + s;
  const float* rp = raw + ((size_t)b * 2048 + l) * 768;
  const unsigned short* qa = resa + (size_t)r * 768;
  const unsigned short* qb = resb + (size_t)r * 768;
  float x[12];
  float sum = 0.f;
  #pragma unroll
  for (int j = 0; j < 3; j++){
    int c4 = lane + j * 64;               // float4 index within the row
    float4 xv = *(const float4*)(rp + c4 * 4);
    ushort4 av = *(const ushort4*)(qa + c4 * 4);
    ushort4 bv = *(const ushort4*)(qb + c4 * 4);
    x[j*4+0] = xv.x + 2.f * (bf2f(av.x) + bf2f(bv.x));
    x[j*4+1] = xv.y + 2.f * (bf2f(av.y) + bf2f(bv.y));
    x[j*4+2] = xv.z + 2.f * (bf2f(av.z) + bf2f(bv.z));
    x[j*4+3] = xv.w + 2.f * (bf2f(av.w) + bf2f(bv.w));
    sum += x[j*4+0] + x[j*4+1] + x[j*4+2] + x[j*4+3];
  }
  #pragma unroll
  for (int o = 1; o < 64; o <<= 1) sum += __shfl_xor(sum, o, 64);
  float mean = sum * (1.f / 768.f);
  float vs = 0.f;
  #pragma unroll
  for (int j = 0; j < 12; j++){ float d = x[j] - mean; vs += d * d; }
  #pragma unroll
  for (int o = 1; o < 64; o <<= 1) vs += __shfl_xor(vs, o, 64);
  float rstd = rsqrtf(vs * (1.f / 768.f) + 1e-12f);
  size_t ob = ((size_t)b * 2048 + l) * 768;
  #pragma unroll
  for (int j = 0; j < 3; j++){
    int c4 = lane + j * 64;
    float4 gv = *(const float4*)(gg + c4 * 4);
    float4 bv = *(const float4*)(bb + c4 * 4);
    ushort4 o;
    o.x = f2bf((x[j*4+0] - mean) * rstd * gv.x + bv.x);
    o.y = f2bf((x[j*4+1] - mean) * rstd * gv.y + bv.y);
    o.z = f2bf((x[j*4+2] - mean) * rstd * gv.z + bv.z);
    o.w = f2bf((x[j*4+3] - mean) * rstd * gv.w + bv.w);
    *(ushort4*)(oe16 + ob + c4 * 4) = o;
  }
}

// ---------------- LN2 + final projection: out[t][0..8], vectorized ----------------
__global__ __launch_bounds__(256)
void k_ln2_out(const unsigned short* __restrict__ ff2, const unsigned short* __restrict__ oe,
               const float* __restrict__ gg, const float* __restrict__ bb,
               const float* __restrict__ Wout, const float* __restrict__ bout,
               float* __restrict__ out)
{
  int wave = threadIdx.x >> 6, lane = threadIdx.x & 63;
  int t = blockIdx.x * 4 + wave;
  const unsigned short* fp = ff2 + (size_t)t * 768;
  const unsigned short* ep = oe  + (size_t)t * 768;
  float x[12];
  float sum = 0.f;
  #pragma unroll
  for (int j = 0; j < 3; j++){
    int c4 = lane + j * 64;
    ushort4 fv = *(const ushort4*)(fp + c4 * 4);
    ushort4 ev = *(const ushort4*)(ep + c4 * 4);
    x[j*4+0] = bf2f(fv.x) + bf2f(ev.x);
    x[j*4+1] = bf2f(fv.y) + bf2f(ev.y);
    x[j*4+2] = bf2f(fv.z) + bf2f(ev.z);
    x[j*4+3] = bf2f(fv.w) + bf2f(ev.w);
    sum += x[j*4+0] + x[j*4+1] + x[j*4+2] + x[j*4+3];
  }
  #pragma unroll
  for (int o = 1; o < 64; o <<= 1) sum += __shfl_xor(sum, o, 64);
  float mean = sum * (1.f / 768.f);
  float vs = 0.f;
  #pragma unroll
  for (int j = 0; j < 12; j++){ float d = x[j] - mean; vs += d * d; }
  #pragma unroll
  for (int o = 1; o < 64; o <<= 1) vs += __shfl_xor(vs, o, 64);
  float rstd = rsqrtf(vs * (1.f / 768.f) + 1e-12f);
  #pragma unroll
  for (int j = 0; j < 3; j++){
    int c4 = lane + j * 64;
    float4 gv = *(const float4*)(gg + c4 * 4);
    float4 bv = *(const float4*)(bb + c4 * 4);
    x[j*4+0] = (x[j*4+0] - mean) * rstd * gv.x + bv.x;
    x[j*4+1] = (x[j*4+1] - mean) * rstd * gv.y + bv.y;
    x[j*4+2] = (x[j*4+2] - mean) * rstd * gv.z + bv.z;
    x[j*4+3] = (x[j*4+3] - mean) * rstd * gv.w + bv.w;
  }
  for (int n = 0; n < 9; n++){
    float p = 0.f;
    #pragma unroll
    for (int j = 0; j < 3; j++){
      int c4 = lane + j * 64;
      float4 wv = *(const float4*)(Wout + n * 768 + c4 * 4);
      p += x[j*4+0] * wv.x + x[j*4+1] * wv.y + x[j*4+2] * wv.z + x[j*4+3] * wv.w;
    }
    #pragma unroll
    for (int o = 1; o < 64; o <<= 1) p += __shfl_xor(p, o, 64);
    if (lane == 0) out[(size_t)t * 9 + n] = p + bout[n];
  }
}

// ---------------------------------------------------------------------------
extern "C" void kernel_launch(void* const* d_in, const int* in_sizes, int n_in,
                              void* d_out, int out_size, void* d_ws, size_t ws_size,
                              hipStream_t stream)
{
  const float* we      = (const float*)d_in[0];
  const int*   starts  = (const int*)d_in[1];
  const int*   tags    = (const int*)d_in[2];
  const float* tag_emb = (const float*)d_in[3];
  const float* sa_Wqkv = (const float*)d_in[4];
  const float* sa_bqkv = (const float*)d_in[5];
  const float* sa_Wo   = (const float*)d_in[6];
  const float* sa_bo   = (const float*)d_in[7];
  const float* at_Wqkv = (const float*)d_in[8];
  const float* at_bqkv = (const float*)d_in[9];
  const float* at_Wo   = (const float*)d_in[10];
  const float* at_bo   = (const float*)d_in[11];
  const float* an_g    = (const float*)d_in[12];
  const float* an_b    = (const float*)d_in[13];
  const float* W1      = (const float*)d_in[14];
  const float* b1      = (const float*)d_in[15];
  const float* W2      = (const float*)d_in[16];
  const float* b2      = (const float*)d_in[17];
  const float* fn_g    = (const float*)d_in[18];
  const float* fn_b    = (const float*)d_in[19];
  const float* Wout    = (const float*)d_in[20];
  const float* bout    = (const float*)d_in[21];
  float* out = (float*)d_out;
  char* ws = (char*)d_ws;

  // ---- workspace layout, 171,442,176 bytes total (lifetime-aliased) ----
  unsigned short* spans   = (unsigned short*)(ws + 0);            // 25,165,824  [16384][768]
  unsigned short* at_in   = (unsigned short*)(ws + 25165824);     // 25,559,040  [256][65][768]
  unsigned short* attno   = (unsigned short*)(ws + 50724864);     // 25,165,824  [16384][768]
  unsigned short* qkv     = (unsigned short*)(ws + 75890688);     // 76,677,120  [<=16640][2304]
  float2*         ropetab = (float2*)(ws + 75890688);             //  6,291,456  (dead before qkv write)
  unsigned short* resa    = (unsigned short*)(ws + 75890688);     // 25,165,824  (over dead qkv)
  unsigned short* resb    = (unsigned short*)(ws + 101056512);    // 25,165,824  (over dead qkv)
  unsigned short* oe16    = (unsigned short*)(ws + 0);            // 25,165,824  (over dead spans)
  unsigned short* ff1     = (unsigned short*)(ws + 25165824);     // 100,663,296 (over dead at_in+attno+res*)
  unsigned short* ff2     = (unsigned short*)(ws + 125829120);    // 25,165,824  (over dead qkv tail)
  unsigned short* wb      = (unsigned short*)(ws + 152567808);    // 18,874,368  bf16 weights
  unsigned short* sa_Wqkv_b = wb;
  unsigned short* sa_Wo_b   = sa_Wqkv_b + 2304 * 768;
  unsigned short* at_Wqkv_b = sa_Wo_b   + 768 * 768;
  unsigned short* at_Wo_b   = at_Wqkv_b + 2304 * 768;
  unsigned short* W1_b      = at_Wo_b   + 768 * 768;
  unsigned short* W2_b      = W1_b      + 3072 * 768;

  // rope table + all weight converts in one launch
  k_prep<<<12288, 256, 0, stream>>>(ropetab, sa_Wqkv, sa_Wo, at_Wqkv, at_Wo, W1, W2, wb);
  // gather+rope + tag-row fill in one launch
  k_gather_rope<<<12544, 256, 0, stream>>>(we, starts, ropetab, spans, tag_emb, tags, at_in);

  // sa QKV:   [16384,768] @ [2304,768]^T -> qkv   (64x9 = 576)
  k_gemm256<0,0><<<576, 512, 0, stream>>>(spans, sa_Wqkv_b, sa_bqkv, qkv, nullptr, 16384, 2304, 768, 9);
  // sa attention
  k_attn<0><<<dim3(12, 256), 64, 0, stream>>>(qkv, attno);
  // sa out-proj + residual(spans), remapped into at_in rows 1..64 per span  (64x3 = 192)
  k_gemm256<1,0><<<192, 512, 0, stream>>>(attno, sa_Wo_b, sa_bo, at_in, spans, 16384, 768, 768, 3);
  // at QKV:  [16640,768] @ [2304,768]^T -> qkv   (65x9 = 585)
  k_gemm256<0,0><<<585, 512, 0, stream>>>(at_in, at_Wqkv_b, at_bqkv, qkv, nullptr, 16640, 2304, 768, 9);
  // at attention (queries = tokens 1..64)
  k_attn<1><<<dim3(12, 256), 64, 0, stream>>>(qkv, attno);
  // at out-proj, split-K=2 -> resa + resb (bf16, span-major)  (2 x 192 = 384 blocks)
  k_gemm256<0,1><<<384, 512, 0, stream>>>(attno, at_Wo_b, at_bo, resa, resb, 16384, 768, 768, 3);
  // LN1: out_emb = LN(raw + 2*(resa+resb)) (scatter folded into row mapping) -> bf16
  k_ln1<<<4096, 256, 0, stream>>>(we, resa, resb, starts, an_g, an_b, oe16);
  // FFN1 + relu -> ff1   (64x12 = 768)
  k_gemm256<3,0><<<768, 512, 0, stream>>>(oe16, W1_b, b1, ff1, nullptr, 16384, 3072, 768, 12);
  // FFN2 -> ff2 (bf16)   (64x3 = 192)
  k_gemm256<0,0><<<192, 512, 0, stream>>>(ff1, W2_b, b2, ff2, nullptr, 16384, 768, 3072, 3);
  // LN2 + final projection
  k_ln2_out<<<4096, 256, 0, stream>>>(ff2, oe16, fn_g, fn_b, Wout, bout, out);
}